// Round 12
// baseline (1847.604 us; speedup 1.0000x reference)
//
#include <hip/hip_runtime.h>
#include <stdint.h>

#define N_ROWS 32768
#define N_E    4096
#define E_DIM  256

typedef __attribute__((ext_vector_type(8))) short short8;
typedef __attribute__((ext_vector_type(4))) float f32x4;

// sortable-uint encoding: order-preserving float -> uint
__device__ __forceinline__ unsigned int f2sort(float s) {
    unsigned int b = __float_as_uint(s);
    return (b & 0x80000000u) ? ~b : (b | 0x80000000u);
}
__device__ __forceinline__ float sort2f(unsigned int u) {
    unsigned int b = (u & 0x80000000u) ? (u ^ 0x80000000u) : ~u;
    return __uint_as_float(b);
}
__device__ __forceinline__ unsigned short bfr(float x) {   // f32 -> bf16 RNE
    unsigned int u = __float_as_uint(x);
    return (unsigned short)((u + 0x7fffu + ((u >> 16) & 1u)) >> 16);
}
__device__ __forceinline__ float bf2f(unsigned short h) {
    return __uint_as_float((unsigned int)h << 16);
}

// ---------- kernel 1: f32 row norms (f64 accumulate, cast f32) ----------
__global__ __launch_bounds__(256) void k_rownorm(const float* __restrict__ src,
                                                 float* __restrict__ outf) {
    int j = blockIdx.x * 4 + (threadIdx.x >> 6);
    int lane = threadIdx.x & 63;
    const float4* e4 = (const float4*)(src + (size_t)j * E_DIM);
    float4 v = e4[lane];
    double s = (double)v.x * v.x + (double)v.y * v.y + (double)v.z * v.z + (double)v.w * v.w;
    #pragma unroll
    for (int off = 1; off < 64; off <<= 1) s += __shfl_xor(s, off);
    if (lane == 0) outf[j] = (float)s;
}

// ---------- kernel 2: bf16 hi/lo split into MFMA fragment-major layout (emb) ----------
__global__ __launch_bounds__(256) void k_split(const float* __restrict__ src,
                                               unsigned short* __restrict__ hi,
                                               unsigned short* __restrict__ lo) {
    int c = blockIdx.x * 256 + threadIdx.x;   // 8-float chunk id
    int r   = c >> 5;
    int kc8 = c & 31;
    const float* p = src + (size_t)c * 8;
    float v[8];
    *(float4*)&v[0] = *(const float4*)p;
    *(float4*)&v[4] = *(const float4*)(p + 4);
    short8 h8, l8;
    #pragma unroll
    for (int t = 0; t < 8; t++) {
        unsigned short h = bfr(v[t]);
        h8[t] = (short)h;
        l8[t] = (short)bfr(v[t] - bf2f(h));
    }
    int kt = kc8 >> 2, lg = kc8 & 3;
    size_t o8 = (size_t)(r >> 4) * 512 + kt * 64 + lg * 16 + (r & 15);
    *(short8*)(hi + o8 * 8) = h8;
    *(short8*)(lo + o8 * 8) = l8;
}

// ---------- kernel 3: MFMA screener on the collapsed-f32 grid ----------
// 64 rows/block, EIGHT waves (512 thr), 2 blocks/CU -> 16 waves/CU (was 8):
// r7-r11 counters showed latency-bound (MfmaUtil 13%, VALU 13%, occ 23%,
// HBM 35% -- nothing saturated). Per p, wave w owns ONE 16-j block.
// Two-pass j-split kept; per-row (K,Q) state in ws between passes.
__global__ __launch_bounds__(512, 4) void k_screen(
        const float* __restrict__ z,
        const unsigned short* __restrict__ ehi, const unsigned short* __restrict__ elo,
        const float* __restrict__ enf, const float* __restrict__ znf,
        int* __restrict__ idx, int* __restrict__ flaglist, int* __restrict__ flagcnt,
        unsigned long long* __restrict__ karr, float* __restrict__ qarr,
        const int jbase, const int finalpass) {
    __shared__ short8 ldsA[4096];              // 64 KB: [0,2048)=Ah, [2048,4096)=Al
    __shared__ float znL[64];
    short8* AhL = ldsA;
    short8* AlL = ldsA + 2048;

    const int tid  = threadIdx.x;
    const int lane = tid & 63;
    const int w    = tid >> 6;                 // wave 0..7
    const int l15  = lane & 15;
    const int lg   = lane >> 4;
    const int rb0  = blockIdx.x * 4;           // base 16-row frag block
    const int row0 = blockIdx.x * 64;

    const short8* Bh = (const short8*)ehi;
    const short8* Bl = (const short8*)elo;

    // ---- stage: read z rows non-temporally, split, write frag-major LDS ----
    #pragma unroll
    for (int i = 0; i < 4; i++) {
        int c   = tid + 512 * i;               // 0..2047 (64 rows x 32 chunks)
        int r   = c >> 5;
        int kc8 = c & 31;
        const f32x4* zp = (const f32x4*)(z + (size_t)(row0 + r) * E_DIM + kc8 * 8);
        f32x4 v0 = __builtin_nontemporal_load(zp);
        f32x4 v1 = __builtin_nontemporal_load(zp + 1);
        float v[8] = {v0.x, v0.y, v0.z, v0.w, v1.x, v1.y, v1.z, v1.w};
        short8 h8, l8;
        #pragma unroll
        for (int t = 0; t < 8; t++) {
            unsigned short h = bfr(v[t]);
            h8[t] = (short)h;
            l8[t] = (short)bfr(v[t] - bf2f(h));
        }
        int o = (r >> 4) * 512 + (kc8 >> 2) * 64 + (kc8 & 3) * 16 + (r & 15);
        AhL[o] = h8;
        AlL[o] = l8;
    }
    if (tid < 64) znL[tid] = znf[row0 + tid];
    __syncthreads();

    unsigned long long K1[16];
    float Qf[16];
    #pragma unroll
    for (int s = 0; s < 16; s++) { K1[s] = ~0ull; Qf[s] = __uint_as_float(0x7F800000u); }

    for (int p = 0; p < 16; ++p) {
        const int jb = (jbase >> 4) + p * 8 + w;   // this wave's 16-j block
        const int bbase = jb * 512 + lane;
        f32x4 acc[4];
        #pragma unroll
        for (int mi = 0; mi < 4; mi++) acc[mi] = (f32x4){0.f, 0.f, 0.f, 0.f};

        short8 pb[2][2];
        pb[0][0] = Bh[bbase];
        pb[0][1] = Bl[bbase];

        #pragma unroll
        for (int kt = 0; kt < 8; kt++) {
            const int cur = kt & 1, nxt = cur ^ 1;
            if (kt < 7) {
                int o = bbase + (kt + 1) * 64;
                pb[nxt][0] = Bh[o];
                pb[nxt][1] = Bl[o];
            }
            short8 ah[4], al[4];
            #pragma unroll
            for (int mi = 0; mi < 4; mi++) {
                int ai = mi * 512 + kt * 64 + lane;
                ah[mi] = AhL[ai];
                al[mi] = AlL[ai];
            }
            #pragma unroll
            for (int mi = 0; mi < 4; mi++) {
                acc[mi] = __builtin_amdgcn_mfma_f32_16x16x32_bf16(ah[mi], pb[cur][0], acc[mi], 0, 0, 0);
                acc[mi] = __builtin_amdgcn_mfma_f32_16x16x32_bf16(al[mi], pb[cur][0], acc[mi], 0, 0, 0);
                acc[mi] = __builtin_amdgcn_mfma_f32_16x16x32_bf16(ah[mi], pb[cur][1], acc[mi], 0, 0, 0);
            }
        }

        int j = jb * 16 + l15;
        float Ce = enf[j];
        #pragma unroll
        for (int mi = 0; mi < 4; mi++) {
            #pragma unroll
            for (int q = 0; q < 4; q++) {
                int s = mi * 4 + q;
                float av = acc[mi][q];
                float A  = znL[mi * 16 + lg * 4 + q] + Ce;  // fl32(Cz+Ce)
                float qv = fmaf(-2.0f, av, A);              // fl32(A-2acc)
                unsigned long long kk =
                    ((unsigned long long)f2sort(qv) << 32) | (unsigned int)j;
                if (kk < K1[s]) K1[s] = kk;
                float res = (A - qv) - 2.0f * av;           // exact rounding residue
                float u = __uint_as_float(__float_as_uint(qv) & 0x7F800000u)
                          * 1.1920929e-7f;                  // ulp(qv)
                if (fabsf(res) > fmaf(0.5f, u, -1.5e-7f))
                    Qf[s] = fminf(Qf[s], qv);
            }
        }
    }

    // A-LDS no longer needed: overlay reduction buffers (sync first)
    __syncthreads();
    unsigned long long* kbuf = (unsigned long long*)ldsA;          // [8][64]
    float* qbuf = (float*)((char*)ldsA + 4096);                    // [8][64]

    #pragma unroll
    for (int s = 0; s < 16; s++) {
        unsigned long long K = K1[s];
        float Q = Qf[s];
        #pragma unroll
        for (int off = 1; off < 16; off <<= 1) {
            unsigned long long ok = __shfl_xor(K, off);
            float oq = __shfl_xor(Q, off);
            if (ok < K) K = ok;
            Q = fminf(Q, oq);
        }
        if (l15 == 0) {
            int r = (s >> 2) * 16 + lg * 4 + (s & 3);
            kbuf[w * 64 + r] = K;
            qbuf[w * 64 + r] = Q;
        }
    }
    __syncthreads();

    if (tid < 64) {
        unsigned long long K = kbuf[tid];
        float Q = qbuf[tid];
        #pragma unroll
        for (int wv = 1; wv < 8; wv++) {
            unsigned long long k2 = kbuf[wv * 64 + tid];
            float q2 = qbuf[wv * 64 + tid];
            if (k2 < K) K = k2;
            Q = fminf(Q, q2);
        }
        int grow = rb0 * 16 + tid;
        if (!finalpass) {
            karr[grow] = K;                    // carry state to pass 1
            qarr[grow] = Q;
        } else {
            unsigned long long kp = karr[grow];
            float qp = qarr[grow];
            if (kp < K) K = kp;
            Q = fminf(Q, qp);
            idx[grow] = (int)(K & 0xFFFFFFFFull);
            float qwin = sort2f((unsigned int)(K >> 32));
            float u = __uint_as_float(__float_as_uint(qwin) & 0x7F800000u) * 1.1920929e-7f;
            if (Q <= fmaf(2.0f, u, qwin)) {    // fragile candidate within 2 grid steps
                int pp = atomicAdd(flagcnt, 1);
                flaglist[pp] = grow;
            }
        }
    }
}

// ---------- kernel 4: exact np-replica repair ----------
// 4 flagged rows per block; thread = 4 j-streams x 4 rows (16 chains) sharing
// each emb load. ascending-k single-acc f32 fma chain; q = fl32(fl32(Cz+Ce)-2acc).
__global__ __launch_bounds__(256) void k_repair(const float* __restrict__ z,
                                                const float* __restrict__ emb,
                                                const float* __restrict__ enf,
                                                const float* __restrict__ znf,
                                                const int* __restrict__ flagcnt,
                                                const int* __restrict__ flaglist,
                                                int* __restrict__ idx) {
    __shared__ float zr[4][E_DIM];
    __shared__ unsigned long long redk[4][4];   // [wave][row]
    const int tid = threadIdx.x;
    const int cnt = flagcnt[0];

    for (int base = blockIdx.x * 4; base < cnt; base += gridDim.x * 4) {
        __syncthreads();                         // protect zr/redk reuse
        int gr[4];
        #pragma unroll
        for (int r = 0; r < 4; r++) {
            int fi = base + r;
            gr[r] = flaglist[fi < cnt ? fi : base];
        }
        #pragma unroll
        for (int r = 0; r < 4; r++)
            zr[r][tid] = z[(size_t)gr[r] * E_DIM + tid];
        __syncthreads();

        float Cz[4];
        #pragma unroll
        for (int r = 0; r < 4; r++) Cz[r] = znf[gr[r]];

        unsigned long long bk[4];
        #pragma unroll
        for (int r = 0; r < 4; r++) bk[r] = ~0ull;

        #pragma unroll
        for (int g = 0; g < 4; g++) {
            const int j0 = tid + 1024 * g;       // streams j0, +256, +512, +768
            const float* e0 = emb + (size_t)(j0      ) * E_DIM;
            const float* e1 = emb + (size_t)(j0 + 256) * E_DIM;
            const float* e2 = emb + (size_t)(j0 + 512) * E_DIM;
            const float* e3 = emb + (size_t)(j0 + 768) * E_DIM;
            float a[4][4];                       // [row][stream]
            #pragma unroll
            for (int r = 0; r < 4; r++)
                #pragma unroll
                for (int s = 0; s < 4; s++) a[r][s] = 0.0f;

            #pragma unroll 4
            for (int k4 = 0; k4 < 64; k4++) {
                float4 v0 = *(const float4*)(e0 + k4 * 4);
                float4 v1 = *(const float4*)(e1 + k4 * 4);
                float4 v2 = *(const float4*)(e2 + k4 * 4);
                float4 v3 = *(const float4*)(e3 + k4 * 4);
                #pragma unroll
                for (int r = 0; r < 4; r++) {
                    float4 zq = *(const float4*)&zr[r][k4 * 4];
                    a[r][0] = fmaf(zq.x, v0.x, a[r][0]); a[r][0] = fmaf(zq.y, v0.y, a[r][0]);
                    a[r][0] = fmaf(zq.z, v0.z, a[r][0]); a[r][0] = fmaf(zq.w, v0.w, a[r][0]);
                    a[r][1] = fmaf(zq.x, v1.x, a[r][1]); a[r][1] = fmaf(zq.y, v1.y, a[r][1]);
                    a[r][1] = fmaf(zq.z, v1.z, a[r][1]); a[r][1] = fmaf(zq.w, v1.w, a[r][1]);
                    a[r][2] = fmaf(zq.x, v2.x, a[r][2]); a[r][2] = fmaf(zq.y, v2.y, a[r][2]);
                    a[r][2] = fmaf(zq.z, v2.z, a[r][2]); a[r][2] = fmaf(zq.w, v2.w, a[r][2]);
                    a[r][3] = fmaf(zq.x, v3.x, a[r][3]); a[r][3] = fmaf(zq.y, v3.y, a[r][3]);
                    a[r][3] = fmaf(zq.z, v3.z, a[r][3]); a[r][3] = fmaf(zq.w, v3.w, a[r][3]);
                }
            }
            float en[4] = {enf[j0], enf[j0 + 256], enf[j0 + 512], enf[j0 + 768]};
            #pragma unroll
            for (int r = 0; r < 4; r++) {
                #pragma unroll
                for (int s = 0; s < 4; s++) {
                    float q = (Cz[r] + en[s]) - 2.0f * a[r][s];
                    unsigned long long k =
                        ((unsigned long long)f2sort(q) << 32) | (unsigned int)(j0 + 256 * s);
                    if (k < bk[r]) bk[r] = k;
                }
            }
        }

        const int w = tid >> 6;
        #pragma unroll
        for (int r = 0; r < 4; r++) {
            unsigned long long K = bk[r];
            #pragma unroll
            for (int off = 1; off < 64; off <<= 1) {
                unsigned long long ok = __shfl_xor(K, off);
                if (ok < K) K = ok;
            }
            if ((tid & 63) == 0) redk[w][r] = K;
        }
        __syncthreads();
        if (tid < 4 && base + tid < cnt) {
            unsigned long long K = redk[0][tid];
            #pragma unroll
            for (int wv = 1; wv < 4; wv++)
                if (redk[wv][tid] < K) K = redk[wv][tid];
            idx[gr[tid]] = (int)(K & 0xFFFFFFFFull);
        }
    }
}

// ---------- kernel 5: epilogue ----------
// d_out FLOAT32: [loss(1) | one-hot(32768*4096) | z_q_st(32768*256) |
//                 emb(4096*256) | indices(32768)]
__global__ __launch_bounds__(256) void k_epilogue(const float* __restrict__ z,
                                                  const float* __restrict__ emb,
                                                  const int* __restrict__ idx,
                                                  float* __restrict__ out,
                                                  double* __restrict__ rowloss) {
    const int row  = blockIdx.x * 4 + (threadIdx.x >> 6);
    const int lane = threadIdx.x & 63;
    const int j    = idx[row];
    float4 zv = *(const float4*)(z   + (size_t)row * E_DIM + lane * 4);
    float4 ev = *(const float4*)(emb + (size_t)j   * E_DIM + lane * 4);

    float4 st;
    st.x = zv.x + (ev.x - zv.x);
    st.y = zv.y + (ev.y - zv.y);
    st.z = zv.z + (ev.z - zv.z);
    st.w = zv.w + (ev.w - zv.w);
    const size_t zq0 = 1ull + (size_t)N_ROWS * N_E;
    *(float4*)(out + zq0 + (size_t)row * E_DIM + lane * 4) = st;

    double dx = (double)ev.x - zv.x, dy = (double)ev.y - zv.y;
    double dz = (double)ev.z - zv.z, dw = (double)ev.w - zv.w;
    double s = dx * dx + dy * dy + dz * dz + dw * dw;
    #pragma unroll
    for (int off = 1; off < 64; off <<= 1) s += __shfl_xor(s, off);

    if (lane == 0) {
        rowloss[row] = s;
        out[1ull + (size_t)row * N_E + j] = 1.0f;
        const size_t ix0 = 1ull + (size_t)N_ROWS * N_E + (size_t)N_ROWS * E_DIM
                         + (size_t)N_E * E_DIM;
        out[ix0 + row] = (float)j;
    }
}

// ---------- kernel 6: deterministic loss reduce ----------
__global__ __launch_bounds__(256) void k_loss(const double* __restrict__ rowloss,
                                              float* __restrict__ out) {
    __shared__ double sm[256];
    double s = 0.0;
    for (int i = threadIdx.x; i < N_ROWS; i += 256) s += rowloss[i];
    sm[threadIdx.x] = s;
    __syncthreads();
    for (int h = 128; h > 0; h >>= 1) {
        if (threadIdx.x < h) sm[threadIdx.x] += sm[threadIdx.x + h];
        __syncthreads();
    }
    if (threadIdx.x == 0)
        out[0] = (float)(sm[0] / ((double)N_ROWS * (double)E_DIM));
}

extern "C" void kernel_launch(void* const* d_in, const int* in_sizes, int n_in,
                              void* d_out, int out_size, void* d_ws, size_t ws_size,
                              hipStream_t stream) {
    const float* z   = (const float*)d_in[0];
    const float* emb = (const float*)d_in[1];
    float* out = (float*)d_out;

    // workspace layout (disjoint, verified; ehi 16B-aligned)
    char* ws = (char*)d_ws;
    float*              enf      = (float*)(ws + 0);                  // 16 KB   -> 16384
    float*              znf      = (float*)(ws + 16384);              // 128 KB  -> 147456
    int*                idx      = (int*)(ws + 147456);               // 128 KB  -> 278528
    int*                flagcnt  = (int*)(ws + 278528);               // 128 B   -> 278656
    int*                flaglist = (int*)(ws + 278656);               // 128 KB  -> 409728
    double*             rowloss  = (double*)(ws + 409728);            // 256 KB  -> 671872
    unsigned long long* karr     = (unsigned long long*)(ws + 671872);// 256 KB  -> 934016
    float*              qarr     = (float*)(ws + 934016);             // 128 KB  -> 1065088
    unsigned short*     ehi      = (unsigned short*)(ws + 1065088);   // 2 MB    -> 3162240
    unsigned short*     elo      = (unsigned short*)(ws + 3162240);   // 2 MB    -> 5259392

    // zero one-hot region + flag counter
    hipMemsetAsync(out + 1, 0, (size_t)N_ROWS * (size_t)N_E * sizeof(float), stream);
    hipMemsetAsync(flagcnt, 0, sizeof(int), stream);

    // emb passthrough chunk: exact d2d copy
    const size_t emb0 = 1ull + (size_t)N_ROWS * N_E + (size_t)N_ROWS * E_DIM;
    hipMemcpyAsync(out + emb0, emb, (size_t)N_E * E_DIM * sizeof(float),
                   hipMemcpyDeviceToDevice, stream);

    k_rownorm <<<N_E / 4, 256, 0, stream>>>(emb, enf);
    k_rownorm <<<N_ROWS / 4, 256, 0, stream>>>(z, znf);
    k_split   <<<N_E / 8, 256, 0, stream>>>(emb, ehi, elo);
    // two-pass screen: each pass's B-half (2 MB) targets per-XCD L2 residency;
    // 512-thr blocks -> 16 waves/CU for latency hiding, full grid co-resident
    k_screen  <<<N_ROWS / 64, 512, 0, stream>>>(z, ehi, elo, enf, znf,
                                                idx, flaglist, flagcnt,
                                                karr, qarr, 0, 0);
    k_screen  <<<N_ROWS / 64, 512, 0, stream>>>(z, ehi, elo, enf, znf,
                                                idx, flaglist, flagcnt,
                                                karr, qarr, 2048, 1);
    k_repair  <<<1024, 256, 0, stream>>>(z, emb, enf, znf, flagcnt, flaglist, idx);
    k_epilogue<<<N_ROWS / 4, 256, 0, stream>>>(z, emb, idx, out, rowloss);
    k_loss    <<<1, 256, 0, stream>>>(rowloss, out);
}

// Round 13
// 1166.638 us; speedup vs baseline: 1.5837x; 1.5837x over previous
//
#include <hip/hip_runtime.h>
#include <stdint.h>

#define N_ROWS 32768
#define N_E    4096
#define E_DIM  256

typedef __attribute__((ext_vector_type(8))) short short8;
typedef __attribute__((ext_vector_type(4))) float f32x4;

// sortable-uint encoding: order-preserving float -> uint
__device__ __forceinline__ unsigned int f2sort(float s) {
    unsigned int b = __float_as_uint(s);
    return (b & 0x80000000u) ? ~b : (b | 0x80000000u);
}
__device__ __forceinline__ float sort2f(unsigned int u) {
    unsigned int b = (u & 0x80000000u) ? (u ^ 0x80000000u) : ~u;
    return __uint_as_float(b);
}
__device__ __forceinline__ unsigned short bfr(float x) {   // f32 -> bf16 RNE
    unsigned int u = __float_as_uint(x);
    return (unsigned short)((u + 0x7fffu + ((u >> 16) & 1u)) >> 16);
}
__device__ __forceinline__ float bf2f(unsigned short h) {
    return __uint_as_float((unsigned int)h << 16);
}

// ---------- kernel 1: f32 row norms (f64 accumulate, cast f32) ----------
__global__ __launch_bounds__(256) void k_rownorm(const float* __restrict__ src,
                                                 float* __restrict__ outf) {
    int j = blockIdx.x * 4 + (threadIdx.x >> 6);
    int lane = threadIdx.x & 63;
    const float4* e4 = (const float4*)(src + (size_t)j * E_DIM);
    float4 v = e4[lane];
    double s = (double)v.x * v.x + (double)v.y * v.y + (double)v.z * v.z + (double)v.w * v.w;
    #pragma unroll
    for (int off = 1; off < 64; off <<= 1) s += __shfl_xor(s, off);
    if (lane == 0) outf[j] = (float)s;
}

// ---------- kernel 2: bf16 hi/lo split into MFMA fragment-major layout (emb) ----------
__global__ __launch_bounds__(256) void k_split(const float* __restrict__ src,
                                               unsigned short* __restrict__ hi,
                                               unsigned short* __restrict__ lo) {
    int c = blockIdx.x * 256 + threadIdx.x;   // 8-float chunk id
    int r   = c >> 5;
    int kc8 = c & 31;
    const float* p = src + (size_t)c * 8;
    float v[8];
    *(float4*)&v[0] = *(const float4*)p;
    *(float4*)&v[4] = *(const float4*)(p + 4);
    short8 h8, l8;
    #pragma unroll
    for (int t = 0; t < 8; t++) {
        unsigned short h = bfr(v[t]);
        h8[t] = (short)h;
        l8[t] = (short)bfr(v[t] - bf2f(h));
    }
    int kt = kc8 >> 2, lg = kc8 & 3;
    size_t o8 = (size_t)(r >> 4) * 512 + kt * 64 + lg * 16 + (r & 15);
    *(short8*)(hi + o8 * 8) = h8;
    *(short8*)(lo + o8 * 8) = l8;
}

// ---------- kernel 3: B-STATIONARY MFMA screener on the collapsed-f32 grid ----------
// Grid = 512 row-chunks x 8 j-stripes; blockIdx = rc*8 + stripe. Under the
// round-robin blockIdx->XCD mapping, stripe s runs ONLY on XCD s, so its
// 512 KB B-slice is permanently L2-resident (r7-r12: A-stationary schedules
// all thrashed L2; inter-block reuse needs the footprint pinned per XCD).
// Per-(row,stripe) partial (K,Q) written to ws; k_merge reduces 8-way.
__global__ __launch_bounds__(256, 2) void k_screen(
        const float* __restrict__ z,
        const unsigned short* __restrict__ ehi, const unsigned short* __restrict__ elo,
        const float* __restrict__ enf, const float* __restrict__ znf,
        unsigned long long* __restrict__ kst, float* __restrict__ qst) {
    __shared__ short8 ldsA[4096];              // 64 KB: [0,2048)=Ah, [2048,4096)=Al
    short8* AhL = ldsA;
    short8* AlL = ldsA + 2048;

    const int tid    = threadIdx.x;
    const int lane   = tid & 63;
    const int w      = tid >> 6;
    const int l15    = lane & 15;
    const int lg     = lane >> 4;
    const int rc     = blockIdx.x >> 3;        // row-chunk 0..511
    const int stripe = blockIdx.x & 7;         // j-stripe 0..7 -> XCD
    const int rb0    = rc * 4;                 // base 16-row frag block
    const int row0   = rc * 64;

    const short8* Bh = (const short8*)ehi;
    const short8* Bl = (const short8*)elo;

    // ---- stage: read z rows non-temporally, split, write frag-major LDS ----
    #pragma unroll
    for (int i = 0; i < 8; i++) {
        int c   = tid + 256 * i;               // 0..2047 (64 rows x 32 chunks)
        int r   = c >> 5;
        int kc8 = c & 31;
        const f32x4* zp = (const f32x4*)(z + (size_t)(row0 + r) * E_DIM + kc8 * 8);
        f32x4 v0 = __builtin_nontemporal_load(zp);
        f32x4 v1 = __builtin_nontemporal_load(zp + 1);
        float v[8] = {v0.x, v0.y, v0.z, v0.w, v1.x, v1.y, v1.z, v1.w};
        short8 h8, l8;
        #pragma unroll
        for (int t = 0; t < 8; t++) {
            unsigned short h = bfr(v[t]);
            h8[t] = (short)h;
            l8[t] = (short)bfr(v[t] - bf2f(h));
        }
        int o = (r >> 4) * 512 + (kc8 >> 2) * 64 + (kc8 & 3) * 16 + (r & 15);
        AhL[o] = h8;
        AlL[o] = l8;
    }
    __syncthreads();

    float czs[16];
    #pragma unroll
    for (int mi = 0; mi < 4; mi++)
        #pragma unroll
        for (int q = 0; q < 4; q++)
            czs[mi * 4 + q] = znf[(rb0 + mi) * 16 + lg * 4 + q];

    unsigned long long K1[16];
    float Qf[16];
    #pragma unroll
    for (int s = 0; s < 16; s++) { K1[s] = ~0ull; Qf[s] = __uint_as_float(0x7F800000u); }

    for (int p = 0; p < 4; ++p) {
        const int jb = stripe * 32 + p * 8 + w * 2;    // 16-j block in stripe
        const int bbase = jb * 512 + lane;
        f32x4 acc[4][2];
        #pragma unroll
        for (int mi = 0; mi < 4; mi++) {
            acc[mi][0] = (f32x4){0.f, 0.f, 0.f, 0.f};
            acc[mi][1] = (f32x4){0.f, 0.f, 0.f, 0.f};
        }

        short8 pb[2][4];
        pb[0][0] = Bh[bbase];       pb[0][1] = Bh[bbase + 512];
        pb[0][2] = Bl[bbase];       pb[0][3] = Bl[bbase + 512];

        #pragma unroll
        for (int kt = 0; kt < 8; kt++) {
            const int cur = kt & 1, nxt = cur ^ 1;
            if (kt < 7) {
                int o = bbase + (kt + 1) * 64;
                pb[nxt][0] = Bh[o];       pb[nxt][1] = Bh[o + 512];
                pb[nxt][2] = Bl[o];       pb[nxt][3] = Bl[o + 512];
            }
            short8 ah[4], al[4];
            #pragma unroll
            for (int mi = 0; mi < 4; mi++) {
                int ai = mi * 512 + kt * 64 + lane;
                ah[mi] = AhL[ai];
                al[mi] = AlL[ai];
            }
            #pragma unroll
            for (int mi = 0; mi < 4; mi++) {
                acc[mi][0] = __builtin_amdgcn_mfma_f32_16x16x32_bf16(ah[mi], pb[cur][0], acc[mi][0], 0, 0, 0);
                acc[mi][1] = __builtin_amdgcn_mfma_f32_16x16x32_bf16(ah[mi], pb[cur][1], acc[mi][1], 0, 0, 0);
                acc[mi][0] = __builtin_amdgcn_mfma_f32_16x16x32_bf16(al[mi], pb[cur][0], acc[mi][0], 0, 0, 0);
                acc[mi][1] = __builtin_amdgcn_mfma_f32_16x16x32_bf16(al[mi], pb[cur][1], acc[mi][1], 0, 0, 0);
                acc[mi][0] = __builtin_amdgcn_mfma_f32_16x16x32_bf16(ah[mi], pb[cur][2], acc[mi][0], 0, 0, 0);
                acc[mi][1] = __builtin_amdgcn_mfma_f32_16x16x32_bf16(ah[mi], pb[cur][3], acc[mi][1], 0, 0, 0);
            }
        }

        #pragma unroll
        for (int jp = 0; jp < 2; jp++) {
            int j = (jb + jp) * 16 + l15;
            float Ce = enf[j];
            #pragma unroll
            for (int mi = 0; mi < 4; mi++) {
                #pragma unroll
                for (int q = 0; q < 4; q++) {
                    int s = mi * 4 + q;
                    float av = acc[mi][jp][q];
                    float A  = czs[s] + Ce;                 // fl32(Cz+Ce)
                    float qv = fmaf(-2.0f, av, A);          // fl32(A-2acc)
                    unsigned long long kk =
                        ((unsigned long long)f2sort(qv) << 32) | (unsigned int)j;
                    if (kk < K1[s]) K1[s] = kk;
                    float res = (A - qv) - 2.0f * av;       // exact rounding residue
                    float u = __uint_as_float(__float_as_uint(qv) & 0x7F800000u)
                              * 1.1920929e-7f;              // ulp(qv)
                    if (fabsf(res) > fmaf(0.5f, u, -1.5e-7f))
                        Qf[s] = fminf(Qf[s], qv);
                }
            }
        }
    }

    // A-LDS no longer needed: overlay reduction buffers (sync first)
    __syncthreads();
    unsigned long long* kbuf = (unsigned long long*)ldsA;          // [4][64]
    float* qbuf = (float*)((char*)ldsA + 2048);                    // [4][64]

    #pragma unroll
    for (int s = 0; s < 16; s++) {
        unsigned long long K = K1[s];
        float Q = Qf[s];
        #pragma unroll
        for (int off = 1; off < 16; off <<= 1) {
            unsigned long long ok = __shfl_xor(K, off);
            float oq = __shfl_xor(Q, off);
            if (ok < K) K = ok;
            Q = fminf(Q, oq);
        }
        if (l15 == 0) {
            int r = (s >> 2) * 16 + lg * 4 + (s & 3);
            kbuf[w * 64 + r] = K;
            qbuf[w * 64 + r] = Q;
        }
    }
    __syncthreads();

    if (tid < 64) {
        unsigned long long K = kbuf[tid];
        float Q = qbuf[tid];
        #pragma unroll
        for (int wv = 1; wv < 4; wv++) {
            unsigned long long k2 = kbuf[wv * 64 + tid];
            float q2 = qbuf[wv * 64 + tid];
            if (k2 < K) K = k2;
            Q = fminf(Q, q2);
        }
        int grow = row0 + tid;
        kst[(size_t)grow * 8 + stripe] = K;    // stripe-partial state
        qst[(size_t)grow * 8 + stripe] = Q;
    }
}

// ---------- kernel 4: 8-way stripe merge + flag/compact ----------
__global__ __launch_bounds__(256) void k_merge(const unsigned long long* __restrict__ kst,
                                               const float* __restrict__ qst,
                                               int* __restrict__ idx,
                                               int* __restrict__ flaglist,
                                               int* __restrict__ flagcnt) {
    int row = blockIdx.x * 256 + threadIdx.x;
    const unsigned long long* kp = kst + (size_t)row * 8;
    const float* qp = qst + (size_t)row * 8;
    unsigned long long K = kp[0];
    float Q = qp[0];
    #pragma unroll
    for (int s = 1; s < 8; s++) {
        unsigned long long k2 = kp[s];
        float q2 = qp[s];
        if (k2 < K) K = k2;
        Q = fminf(Q, q2);
    }
    idx[row] = (int)(K & 0xFFFFFFFFull);
    float qwin = sort2f((unsigned int)(K >> 32));
    float u = __uint_as_float(__float_as_uint(qwin) & 0x7F800000u) * 1.1920929e-7f;
    if (Q <= fmaf(2.0f, u, qwin)) {            // fragile candidate within 2 grid steps
        int pp = atomicAdd(flagcnt, 1);
        flaglist[pp] = row;
    }
}

// ---------- kernel 5: exact np-replica repair ----------
// 4 flagged rows per block; thread = 4 j-streams x 4 rows (16 chains) sharing
// each emb load. ascending-k single-acc f32 fma chain; q = fl32(fl32(Cz+Ce)-2acc).
__global__ __launch_bounds__(256) void k_repair(const float* __restrict__ z,
                                                const float* __restrict__ emb,
                                                const float* __restrict__ enf,
                                                const float* __restrict__ znf,
                                                const int* __restrict__ flagcnt,
                                                const int* __restrict__ flaglist,
                                                int* __restrict__ idx) {
    __shared__ float zr[4][E_DIM];
    __shared__ unsigned long long redk[4][4];   // [wave][row]
    const int tid = threadIdx.x;
    const int cnt = flagcnt[0];

    for (int base = blockIdx.x * 4; base < cnt; base += gridDim.x * 4) {
        __syncthreads();                         // protect zr/redk reuse
        int gr[4];
        #pragma unroll
        for (int r = 0; r < 4; r++) {
            int fi = base + r;
            gr[r] = flaglist[fi < cnt ? fi : base];
        }
        #pragma unroll
        for (int r = 0; r < 4; r++)
            zr[r][tid] = z[(size_t)gr[r] * E_DIM + tid];
        __syncthreads();

        float Cz[4];
        #pragma unroll
        for (int r = 0; r < 4; r++) Cz[r] = znf[gr[r]];

        unsigned long long bk[4];
        #pragma unroll
        for (int r = 0; r < 4; r++) bk[r] = ~0ull;

        #pragma unroll
        for (int g = 0; g < 4; g++) {
            const int j0 = tid + 1024 * g;       // streams j0, +256, +512, +768
            const float* e0 = emb + (size_t)(j0      ) * E_DIM;
            const float* e1 = emb + (size_t)(j0 + 256) * E_DIM;
            const float* e2 = emb + (size_t)(j0 + 512) * E_DIM;
            const float* e3 = emb + (size_t)(j0 + 768) * E_DIM;
            float a[4][4];                       // [row][stream]
            #pragma unroll
            for (int r = 0; r < 4; r++)
                #pragma unroll
                for (int s = 0; s < 4; s++) a[r][s] = 0.0f;

            #pragma unroll 4
            for (int k4 = 0; k4 < 64; k4++) {
                float4 v0 = *(const float4*)(e0 + k4 * 4);
                float4 v1 = *(const float4*)(e1 + k4 * 4);
                float4 v2 = *(const float4*)(e2 + k4 * 4);
                float4 v3 = *(const float4*)(e3 + k4 * 4);
                #pragma unroll
                for (int r = 0; r < 4; r++) {
                    float4 zq = *(const float4*)&zr[r][k4 * 4];
                    a[r][0] = fmaf(zq.x, v0.x, a[r][0]); a[r][0] = fmaf(zq.y, v0.y, a[r][0]);
                    a[r][0] = fmaf(zq.z, v0.z, a[r][0]); a[r][0] = fmaf(zq.w, v0.w, a[r][0]);
                    a[r][1] = fmaf(zq.x, v1.x, a[r][1]); a[r][1] = fmaf(zq.y, v1.y, a[r][1]);
                    a[r][1] = fmaf(zq.z, v1.z, a[r][1]); a[r][1] = fmaf(zq.w, v1.w, a[r][1]);
                    a[r][2] = fmaf(zq.x, v2.x, a[r][2]); a[r][2] = fmaf(zq.y, v2.y, a[r][2]);
                    a[r][2] = fmaf(zq.z, v2.z, a[r][2]); a[r][2] = fmaf(zq.w, v2.w, a[r][2]);
                    a[r][3] = fmaf(zq.x, v3.x, a[r][3]); a[r][3] = fmaf(zq.y, v3.y, a[r][3]);
                    a[r][3] = fmaf(zq.z, v3.z, a[r][3]); a[r][3] = fmaf(zq.w, v3.w, a[r][3]);
                }
            }
            float en[4] = {enf[j0], enf[j0 + 256], enf[j0 + 512], enf[j0 + 768]};
            #pragma unroll
            for (int r = 0; r < 4; r++) {
                #pragma unroll
                for (int s = 0; s < 4; s++) {
                    float q = (Cz[r] + en[s]) - 2.0f * a[r][s];
                    unsigned long long k =
                        ((unsigned long long)f2sort(q) << 32) | (unsigned int)(j0 + 256 * s);
                    if (k < bk[r]) bk[r] = k;
                }
            }
        }

        const int w = tid >> 6;
        #pragma unroll
        for (int r = 0; r < 4; r++) {
            unsigned long long K = bk[r];
            #pragma unroll
            for (int off = 1; off < 64; off <<= 1) {
                unsigned long long ok = __shfl_xor(K, off);
                if (ok < K) K = ok;
            }
            if ((tid & 63) == 0) redk[w][r] = K;
        }
        __syncthreads();
        if (tid < 4 && base + tid < cnt) {
            unsigned long long K = redk[0][tid];
            #pragma unroll
            for (int wv = 1; wv < 4; wv++)
                if (redk[wv][tid] < K) K = redk[wv][tid];
            idx[gr[tid]] = (int)(K & 0xFFFFFFFFull);
        }
    }
}

// ---------- kernel 6: epilogue ----------
// d_out FLOAT32: [loss(1) | one-hot(32768*4096) | z_q_st(32768*256) |
//                 emb(4096*256) | indices(32768)]
__global__ __launch_bounds__(256) void k_epilogue(const float* __restrict__ z,
                                                  const float* __restrict__ emb,
                                                  const int* __restrict__ idx,
                                                  float* __restrict__ out,
                                                  double* __restrict__ rowloss) {
    const int row  = blockIdx.x * 4 + (threadIdx.x >> 6);
    const int lane = threadIdx.x & 63;
    const int j    = idx[row];
    float4 zv = *(const float4*)(z   + (size_t)row * E_DIM + lane * 4);
    float4 ev = *(const float4*)(emb + (size_t)j   * E_DIM + lane * 4);

    float4 st;
    st.x = zv.x + (ev.x - zv.x);
    st.y = zv.y + (ev.y - zv.y);
    st.z = zv.z + (ev.z - zv.z);
    st.w = zv.w + (ev.w - zv.w);
    const size_t zq0 = 1ull + (size_t)N_ROWS * N_E;
    *(float4*)(out + zq0 + (size_t)row * E_DIM + lane * 4) = st;

    double dx = (double)ev.x - zv.x, dy = (double)ev.y - zv.y;
    double dz = (double)ev.z - zv.z, dw = (double)ev.w - zv.w;
    double s = dx * dx + dy * dy + dz * dz + dw * dw;
    #pragma unroll
    for (int off = 1; off < 64; off <<= 1) s += __shfl_xor(s, off);

    if (lane == 0) {
        rowloss[row] = s;
        out[1ull + (size_t)row * N_E + j] = 1.0f;
        const size_t ix0 = 1ull + (size_t)N_ROWS * N_E + (size_t)N_ROWS * E_DIM
                         + (size_t)N_E * E_DIM;
        out[ix0 + row] = (float)j;
    }
}

// ---------- kernel 7: deterministic loss reduce ----------
__global__ __launch_bounds__(256) void k_loss(const double* __restrict__ rowloss,
                                              float* __restrict__ out) {
    __shared__ double sm[256];
    double s = 0.0;
    for (int i = threadIdx.x; i < N_ROWS; i += 256) s += rowloss[i];
    sm[threadIdx.x] = s;
    __syncthreads();
    for (int h = 128; h > 0; h >>= 1) {
        if (threadIdx.x < h) sm[threadIdx.x] += sm[threadIdx.x + h];
        __syncthreads();
    }
    if (threadIdx.x == 0)
        out[0] = (float)(sm[0] / ((double)N_ROWS * (double)E_DIM));
}

extern "C" void kernel_launch(void* const* d_in, const int* in_sizes, int n_in,
                              void* d_out, int out_size, void* d_ws, size_t ws_size,
                              hipStream_t stream) {
    const float* z   = (const float*)d_in[0];
    const float* emb = (const float*)d_in[1];
    float* out = (float*)d_out;

    // workspace layout (disjoint, 16B-aligned)
    char* ws = (char*)d_ws;
    float*              enf      = (float*)(ws + 0);                  // 16 KB   -> 16384
    float*              znf      = (float*)(ws + 16384);              // 128 KB  -> 147456
    int*                idx      = (int*)(ws + 147456);               // 128 KB  -> 278528
    int*                flagcnt  = (int*)(ws + 278528);               // 128 B   -> 278656
    int*                flaglist = (int*)(ws + 278656);               // 128 KB  -> 409728
    double*             rowloss  = (double*)(ws + 409728);            // 256 KB  -> 671872
    unsigned long long* kst      = (unsigned long long*)(ws + 671872);// 2 MB    -> 2768896
    float*              qst      = (float*)(ws + 2768896);            // 1 MB    -> 3817472
    unsigned short*     ehi      = (unsigned short*)(ws + 3817472);   // 2 MB    -> 5914624
    unsigned short*     elo      = (unsigned short*)(ws + 5914624);   // 2 MB    -> 8011776

    // zero one-hot region + flag counter
    hipMemsetAsync(out + 1, 0, (size_t)N_ROWS * (size_t)N_E * sizeof(float), stream);
    hipMemsetAsync(flagcnt, 0, sizeof(int), stream);

    // emb passthrough chunk: exact d2d copy
    const size_t emb0 = 1ull + (size_t)N_ROWS * N_E + (size_t)N_ROWS * E_DIM;
    hipMemcpyAsync(out + emb0, emb, (size_t)N_E * E_DIM * sizeof(float),
                   hipMemcpyDeviceToDevice, stream);

    k_rownorm <<<N_E / 4, 256, 0, stream>>>(emb, enf);
    k_rownorm <<<N_ROWS / 4, 256, 0, stream>>>(z, znf);
    k_split   <<<N_E / 8, 256, 0, stream>>>(emb, ehi, elo);
    // B-stationary: 512 row-chunks x 8 XCD-pinned j-stripes
    k_screen  <<<(N_ROWS / 64) * 8, 256, 0, stream>>>(z, ehi, elo, enf, znf, kst, qst);
    k_merge   <<<N_ROWS / 256, 256, 0, stream>>>(kst, qst, idx, flaglist, flagcnt);
    k_repair  <<<1024, 256, 0, stream>>>(z, emb, enf, znf, flagcnt, flaglist, idx);
    k_epilogue<<<N_ROWS / 4, 256, 0, stream>>>(z, emb, idx, out, rowloss);
    k_loss    <<<1, 256, 0, stream>>>(rowloss, out);
}

// Round 14
// 801.600 us; speedup vs baseline: 2.3049x; 1.4554x over previous
//
#include <hip/hip_runtime.h>
#include <stdint.h>

#define N_ROWS 32768
#define N_E    4096
#define E_DIM  256

typedef __attribute__((ext_vector_type(8))) short short8;
typedef __attribute__((ext_vector_type(4))) float f32x4;

// sortable-uint encoding: order-preserving float -> uint
__device__ __forceinline__ unsigned int f2sort(float s) {
    unsigned int b = __float_as_uint(s);
    return (b & 0x80000000u) ? ~b : (b | 0x80000000u);
}
__device__ __forceinline__ float sort2f(unsigned int u) {
    unsigned int b = (u & 0x80000000u) ? (u ^ 0x80000000u) : ~u;
    return __uint_as_float(b);
}
__device__ __forceinline__ unsigned short bfr(float x) {   // f32 -> bf16 RNE
    unsigned int u = __float_as_uint(x);
    return (unsigned short)((u + 0x7fffu + ((u >> 16) & 1u)) >> 16);
}
__device__ __forceinline__ float bf2f(unsigned short h) {
    return __uint_as_float((unsigned int)h << 16);
}

// ---------- kernel 1: f32 row norms (f64 accumulate, cast f32) ----------
__global__ __launch_bounds__(256) void k_rownorm(const float* __restrict__ src,
                                                 float* __restrict__ outf) {
    int j = blockIdx.x * 4 + (threadIdx.x >> 6);
    int lane = threadIdx.x & 63;
    const float4* e4 = (const float4*)(src + (size_t)j * E_DIM);
    float4 v = e4[lane];
    double s = (double)v.x * v.x + (double)v.y * v.y + (double)v.z * v.z + (double)v.w * v.w;
    #pragma unroll
    for (int off = 1; off < 64; off <<= 1) s += __shfl_xor(s, off);
    if (lane == 0) outf[j] = (float)s;
}

// ---------- kernel 2: bf16 hi/lo split into MFMA fragment-major layout ----------
__global__ __launch_bounds__(256) void k_split(const float* __restrict__ src,
                                               unsigned short* __restrict__ hi,
                                               unsigned short* __restrict__ lo) {
    int c = blockIdx.x * 256 + threadIdx.x;   // 8-float chunk id
    int r   = c >> 5;
    int kc8 = c & 31;
    const float* p = src + (size_t)c * 8;
    float v[8];
    *(float4*)&v[0] = *(const float4*)p;
    *(float4*)&v[4] = *(const float4*)(p + 4);
    short8 h8, l8;
    #pragma unroll
    for (int t = 0; t < 8; t++) {
        unsigned short h = bfr(v[t]);
        h8[t] = (short)h;
        l8[t] = (short)bfr(v[t] - bf2f(h));
    }
    int kt = kc8 >> 2, lg = kc8 & 3;
    size_t o8 = (size_t)(r >> 4) * 512 + kt * 64 + lg * 16 + (r & 15);
    *(short8*)(hi + o8 * 8) = h8;
    *(short8*)(lo + o8 * 8) = l8;
}

// ---------- kernel 3: z-IN-REGISTERS / B-THROUGH-LDS MFMA screener ----------
// Grid = 256 blocks (1/CU via 128 KB LDS, all co-resident). Block owns 128
// rows; wave holds its 32 rows' A-frags (hi+lo) in 128 VGPR, loaded ONCE.
// jt-loop stages 32 B-tiles (128 j, full K) through LDS. After the z
// prologue the L2 carries ONLY B (4 MB unique = per-XCD L2 capacity), so
// residency is guaranteed by capacity, not scheduling (r7-r13 lesson: the
// recurring z re-staging was flushing L2 every generation).
__global__ __launch_bounds__(256, 1) void k_screen(
        const unsigned short* __restrict__ zhi, const unsigned short* __restrict__ zlo,
        const unsigned short* __restrict__ ehi, const unsigned short* __restrict__ elo,
        const float* __restrict__ enf, const float* __restrict__ znf,
        int* __restrict__ idx, int* __restrict__ flaglist, int* __restrict__ flagcnt) {
    __shared__ short8 BhL[4096];               // 64 KB: tile hi (128 j x 256 k)
    __shared__ short8 BlL[4096];               // 64 KB: tile lo

    const int tid  = threadIdx.x;
    const int lane = tid & 63;
    const int w    = tid >> 6;                 // wave 0..3
    const int l15  = lane & 15;
    const int lg   = lane >> 4;
    const int fb0  = blockIdx.x * 8 + w * 2;   // wave's first 16-row frag block

    const short8* Ah = (const short8*)zhi;
    const short8* Al = (const short8*)zlo;
    const short8* Gh = (const short8*)ehi;
    const short8* Gl = (const short8*)elo;

    // ---- prologue: wave's 32 rows of A (hi+lo) -> 128 VGPR, loaded once ----
    short8 ah[2][8], al[2][8];
    #pragma unroll
    for (int mi = 0; mi < 2; mi++)
        #pragma unroll
        for (int kt = 0; kt < 8; kt++) {
            size_t o = (size_t)(fb0 + mi) * 512 + kt * 64 + lane;
            ah[mi][kt] = Ah[o];
            al[mi][kt] = Al[o];
        }

    float czs[8];
    #pragma unroll
    for (int mi = 0; mi < 2; mi++)
        #pragma unroll
        for (int qi = 0; qi < 4; qi++)
            czs[mi * 4 + qi] = znf[(fb0 + mi) * 16 + lg * 4 + qi];

    unsigned long long K1[8];
    float Qf[8];
    #pragma unroll
    for (int s = 0; s < 8; s++) { K1[s] = ~0ull; Qf[s] = __uint_as_float(0x7F800000u); }

    for (int jt = 0; jt < 32; ++jt) {
        __syncthreads();                       // prev tile fully consumed
        // ---- stage B-tile (128 j x 256 k, hi+lo) ----
        #pragma unroll
        for (int i = 0; i < 16; i++) {
            int c = tid + 256 * i;             // 0..4095
            BhL[c] = Gh[(size_t)jt * 4096 + c];
            BlL[c] = Gl[(size_t)jt * 4096 + c];
        }
        __syncthreads();

        f32x4 acc[2][8];
        #pragma unroll
        for (int mi = 0; mi < 2; mi++)
            #pragma unroll
            for (int p = 0; p < 8; p++)
                acc[mi][p] = (f32x4){0.f, 0.f, 0.f, 0.f};

        #pragma unroll
        for (int kt = 0; kt < 8; kt++) {
            short8 bh[8], bl[8];
            #pragma unroll
            for (int p = 0; p < 8; p++) {
                bh[p] = BhL[p * 512 + kt * 64 + lane];
                bl[p] = BlL[p * 512 + kt * 64 + lane];
            }
            #pragma unroll
            for (int p = 0; p < 8; p++) {
                #pragma unroll
                for (int mi = 0; mi < 2; mi++) {
                    acc[mi][p] = __builtin_amdgcn_mfma_f32_16x16x32_bf16(ah[mi][kt], bh[p], acc[mi][p], 0, 0, 0);
                    acc[mi][p] = __builtin_amdgcn_mfma_f32_16x16x32_bf16(al[mi][kt], bh[p], acc[mi][p], 0, 0, 0);
                    acc[mi][p] = __builtin_amdgcn_mfma_f32_16x16x32_bf16(ah[mi][kt], bl[p], acc[mi][p], 0, 0, 0);
                }
            }
        }

        // ---- fold tile into running per-row (K,Q) on the collapsed grid ----
        #pragma unroll
        for (int p = 0; p < 8; p++) {
            int j = jt * 128 + p * 16 + l15;
            float Ce = enf[j];
            #pragma unroll
            for (int mi = 0; mi < 2; mi++) {
                #pragma unroll
                for (int qi = 0; qi < 4; qi++) {
                    int s = mi * 4 + qi;
                    float av = acc[mi][p][qi];
                    float A  = czs[s] + Ce;                 // fl32(Cz+Ce)
                    float qv = fmaf(-2.0f, av, A);          // fl32(A-2acc)
                    unsigned long long kk =
                        ((unsigned long long)f2sort(qv) << 32) | (unsigned int)j;
                    if (kk < K1[s]) K1[s] = kk;
                    float res = (A - qv) - 2.0f * av;       // exact rounding residue
                    float u = __uint_as_float(__float_as_uint(qv) & 0x7F800000u)
                              * 1.1920929e-7f;              // ulp(qv)
                    if (fabsf(res) > fmaf(0.5f, u, -1.5e-7f))
                        Qf[s] = fminf(Qf[s], qv);
                }
            }
        }
    }

    // ---- final: reduce over l15 lanes; waves own disjoint rows ----
    #pragma unroll
    for (int s = 0; s < 8; s++) {
        unsigned long long K = K1[s];
        float Q = Qf[s];
        #pragma unroll
        for (int off = 1; off < 16; off <<= 1) {
            unsigned long long ok = __shfl_xor(K, off);
            float oq = __shfl_xor(Q, off);
            if (ok < K) K = ok;
            Q = fminf(Q, oq);
        }
        if (l15 == 0) {
            int row = blockIdx.x * 128 + w * 32 + (s >> 2) * 16 + lg * 4 + (s & 3);
            idx[row] = (int)(K & 0xFFFFFFFFull);
            float qwin = sort2f((unsigned int)(K >> 32));
            float u = __uint_as_float(__float_as_uint(qwin) & 0x7F800000u) * 1.1920929e-7f;
            if (Q <= fmaf(2.0f, u, qwin)) {    // fragile candidate within 2 grid steps
                int pp = atomicAdd(flagcnt, 1);
                flaglist[pp] = row;
            }
        }
    }
}

// ---------- kernel 4: exact np-replica repair ----------
// ascending-k single-acc f32 fma chain; q = fl32(fl32(Cz+Ce) - 2*acc).
__global__ __launch_bounds__(256) void k_repair(const float* __restrict__ z,
                                                const float* __restrict__ emb,
                                                const float* __restrict__ enf,
                                                const float* __restrict__ znf,
                                                const int* __restrict__ flagcnt,
                                                const int* __restrict__ flaglist,
                                                int* __restrict__ idx) {
    __shared__ float zr[4][E_DIM];
    __shared__ unsigned long long redk[4][4];   // [wave][row]
    const int tid = threadIdx.x;
    const int cnt = flagcnt[0];

    for (int base = blockIdx.x * 4; base < cnt; base += gridDim.x * 4) {
        __syncthreads();                         // protect zr/redk reuse
        int gr[4];
        #pragma unroll
        for (int r = 0; r < 4; r++) {
            int fi = base + r;
            gr[r] = flaglist[fi < cnt ? fi : base];
        }
        #pragma unroll
        for (int r = 0; r < 4; r++)
            zr[r][tid] = z[(size_t)gr[r] * E_DIM + tid];
        __syncthreads();

        float Cz[4];
        #pragma unroll
        for (int r = 0; r < 4; r++) Cz[r] = znf[gr[r]];

        unsigned long long bk[4];
        #pragma unroll
        for (int r = 0; r < 4; r++) bk[r] = ~0ull;

        #pragma unroll
        for (int g = 0; g < 4; g++) {
            const int j0 = tid + 1024 * g;       // streams j0, +256, +512, +768
            const float* e0 = emb + (size_t)(j0      ) * E_DIM;
            const float* e1 = emb + (size_t)(j0 + 256) * E_DIM;
            const float* e2 = emb + (size_t)(j0 + 512) * E_DIM;
            const float* e3 = emb + (size_t)(j0 + 768) * E_DIM;
            float a[4][4];                       // [row][stream]
            #pragma unroll
            for (int r = 0; r < 4; r++)
                #pragma unroll
                for (int s = 0; s < 4; s++) a[r][s] = 0.0f;

            #pragma unroll 4
            for (int k4 = 0; k4 < 64; k4++) {
                float4 v0 = *(const float4*)(e0 + k4 * 4);
                float4 v1 = *(const float4*)(e1 + k4 * 4);
                float4 v2 = *(const float4*)(e2 + k4 * 4);
                float4 v3 = *(const float4*)(e3 + k4 * 4);
                #pragma unroll
                for (int r = 0; r < 4; r++) {
                    float4 zq = *(const float4*)&zr[r][k4 * 4];
                    a[r][0] = fmaf(zq.x, v0.x, a[r][0]); a[r][0] = fmaf(zq.y, v0.y, a[r][0]);
                    a[r][0] = fmaf(zq.z, v0.z, a[r][0]); a[r][0] = fmaf(zq.w, v0.w, a[r][0]);
                    a[r][1] = fmaf(zq.x, v1.x, a[r][1]); a[r][1] = fmaf(zq.y, v1.y, a[r][1]);
                    a[r][1] = fmaf(zq.z, v1.z, a[r][1]); a[r][1] = fmaf(zq.w, v1.w, a[r][1]);
                    a[r][2] = fmaf(zq.x, v2.x, a[r][2]); a[r][2] = fmaf(zq.y, v2.y, a[r][2]);
                    a[r][2] = fmaf(zq.z, v2.z, a[r][2]); a[r][2] = fmaf(zq.w, v2.w, a[r][2]);
                    a[r][3] = fmaf(zq.x, v3.x, a[r][3]); a[r][3] = fmaf(zq.y, v3.y, a[r][3]);
                    a[r][3] = fmaf(zq.z, v3.z, a[r][3]); a[r][3] = fmaf(zq.w, v3.w, a[r][3]);
                }
            }
            float en[4] = {enf[j0], enf[j0 + 256], enf[j0 + 512], enf[j0 + 768]};
            #pragma unroll
            for (int r = 0; r < 4; r++) {
                #pragma unroll
                for (int s = 0; s < 4; s++) {
                    float q = (Cz[r] + en[s]) - 2.0f * a[r][s];
                    unsigned long long k =
                        ((unsigned long long)f2sort(q) << 32) | (unsigned int)(j0 + 256 * s);
                    if (k < bk[r]) bk[r] = k;
                }
            }
        }

        const int w = tid >> 6;
        #pragma unroll
        for (int r = 0; r < 4; r++) {
            unsigned long long K = bk[r];
            #pragma unroll
            for (int off = 1; off < 64; off <<= 1) {
                unsigned long long ok = __shfl_xor(K, off);
                if (ok < K) K = ok;
            }
            if ((tid & 63) == 0) redk[w][r] = K;
        }
        __syncthreads();
        if (tid < 4 && base + tid < cnt) {
            unsigned long long K = redk[0][tid];
            #pragma unroll
            for (int wv = 1; wv < 4; wv++)
                if (redk[wv][tid] < K) K = redk[wv][tid];
            idx[gr[tid]] = (int)(K & 0xFFFFFFFFull);
        }
    }
}

// ---------- kernel 5: epilogue ----------
// d_out FLOAT32: [loss(1) | one-hot(32768*4096) | z_q_st(32768*256) |
//                 emb(4096*256) | indices(32768)]
__global__ __launch_bounds__(256) void k_epilogue(const float* __restrict__ z,
                                                  const float* __restrict__ emb,
                                                  const int* __restrict__ idx,
                                                  float* __restrict__ out,
                                                  double* __restrict__ rowloss) {
    const int row  = blockIdx.x * 4 + (threadIdx.x >> 6);
    const int lane = threadIdx.x & 63;
    const int j    = idx[row];
    float4 zv = *(const float4*)(z   + (size_t)row * E_DIM + lane * 4);
    float4 ev = *(const float4*)(emb + (size_t)j   * E_DIM + lane * 4);

    float4 st;
    st.x = zv.x + (ev.x - zv.x);
    st.y = zv.y + (ev.y - zv.y);
    st.z = zv.z + (ev.z - zv.z);
    st.w = zv.w + (ev.w - zv.w);
    const size_t zq0 = 1ull + (size_t)N_ROWS * N_E;
    *(float4*)(out + zq0 + (size_t)row * E_DIM + lane * 4) = st;

    double dx = (double)ev.x - zv.x, dy = (double)ev.y - zv.y;
    double dz = (double)ev.z - zv.z, dw = (double)ev.w - zv.w;
    double s = dx * dx + dy * dy + dz * dz + dw * dw;
    #pragma unroll
    for (int off = 1; off < 64; off <<= 1) s += __shfl_xor(s, off);

    if (lane == 0) {
        rowloss[row] = s;
        out[1ull + (size_t)row * N_E + j] = 1.0f;
        const size_t ix0 = 1ull + (size_t)N_ROWS * N_E + (size_t)N_ROWS * E_DIM
                         + (size_t)N_E * E_DIM;
        out[ix0 + row] = (float)j;
    }
}

// ---------- kernel 6: deterministic loss reduce ----------
__global__ __launch_bounds__(256) void k_loss(const double* __restrict__ rowloss,
                                              float* __restrict__ out) {
    __shared__ double sm[256];
    double s = 0.0;
    for (int i = threadIdx.x; i < N_ROWS; i += 256) s += rowloss[i];
    sm[threadIdx.x] = s;
    __syncthreads();
    for (int h = 128; h > 0; h >>= 1) {
        if (threadIdx.x < h) sm[threadIdx.x] += sm[threadIdx.x + h];
        __syncthreads();
    }
    if (threadIdx.x == 0)
        out[0] = (float)(sm[0] / ((double)N_ROWS * (double)E_DIM));
}

extern "C" void kernel_launch(void* const* d_in, const int* in_sizes, int n_in,
                              void* d_out, int out_size, void* d_ws, size_t ws_size,
                              hipStream_t stream) {
    const float* z   = (const float*)d_in[0];
    const float* emb = (const float*)d_in[1];
    float* out = (float*)d_out;

    // workspace layout (disjoint, 16B-aligned)
    char* ws = (char*)d_ws;
    float*          enf      = (float*)(ws + 0);                  // 16 KB   -> 16384
    float*          znf      = (float*)(ws + 16384);              // 128 KB  -> 147456
    int*            idx      = (int*)(ws + 147456);               // 128 KB  -> 278528
    int*            flagcnt  = (int*)(ws + 278528);               // 128 B   -> 278656
    int*            flaglist = (int*)(ws + 278656);               // 128 KB  -> 409728
    double*         rowloss  = (double*)(ws + 409728);            // 256 KB  -> 671872
    unsigned short* zhi      = (unsigned short*)(ws + 671872);    // 16 MB   -> 17449088
    unsigned short* zlo      = (unsigned short*)(ws + 17449088);  // 16 MB   -> 34226304
    unsigned short* ehi      = (unsigned short*)(ws + 34226304);  // 2 MB    -> 36323456
    unsigned short* elo      = (unsigned short*)(ws + 36323456);  // 2 MB    -> 38420608

    // zero one-hot region + flag counter
    hipMemsetAsync(out + 1, 0, (size_t)N_ROWS * (size_t)N_E * sizeof(float), stream);
    hipMemsetAsync(flagcnt, 0, sizeof(int), stream);

    // emb passthrough chunk: exact d2d copy
    const size_t emb0 = 1ull + (size_t)N_ROWS * N_E + (size_t)N_ROWS * E_DIM;
    hipMemcpyAsync(out + emb0, emb, (size_t)N_E * E_DIM * sizeof(float),
                   hipMemcpyDeviceToDevice, stream);

    k_rownorm <<<N_E / 4, 256, 0, stream>>>(emb, enf);
    k_rownorm <<<N_ROWS / 4, 256, 0, stream>>>(z, znf);
    k_split   <<<N_E / 8, 256, 0, stream>>>(emb, ehi, elo);
    k_split   <<<N_ROWS / 8, 256, 0, stream>>>(z, zhi, zlo);
    // z-in-registers / B-through-LDS screener: grid == CU count
    k_screen  <<<256, 256, 0, stream>>>(zhi, zlo, ehi, elo, enf, znf,
                                        idx, flaglist, flagcnt);
    k_repair  <<<1024, 256, 0, stream>>>(z, emb, enf, znf, flagcnt, flaglist, idx);
    k_epilogue<<<N_ROWS / 4, 256, 0, stream>>>(z, emb, idx, out, rowloss);
    k_loss    <<<1, 256, 0, stream>>>(rowloss, out);
}

// Round 15
// 596.575 us; speedup vs baseline: 3.0970x; 1.3437x over previous
//
#include <hip/hip_runtime.h>
#include <stdint.h>

#define N_ROWS 32768
#define N_E    4096
#define E_DIM  256

typedef __attribute__((ext_vector_type(8))) short short8;
typedef __attribute__((ext_vector_type(4))) float f32x4;

// async global->LDS 16B: dest = wave-uniform LDS base + lane*16
#define GLOAD_LDS16(g, l)                                                     \
    __builtin_amdgcn_global_load_lds(                                         \
        (const __attribute__((address_space(1))) void*)(g),                   \
        (__attribute__((address_space(3))) void*)(l), 16, 0, 0)

// sortable-uint encoding: order-preserving float -> uint
__device__ __forceinline__ unsigned int f2sort(float s) {
    unsigned int b = __float_as_uint(s);
    return (b & 0x80000000u) ? ~b : (b | 0x80000000u);
}
__device__ __forceinline__ float sort2f(unsigned int u) {
    unsigned int b = (u & 0x80000000u) ? (u ^ 0x80000000u) : ~u;
    return __uint_as_float(b);
}
__device__ __forceinline__ unsigned short bfr(float x) {   // f32 -> bf16 RNE
    unsigned int u = __float_as_uint(x);
    return (unsigned short)((u + 0x7fffu + ((u >> 16) & 1u)) >> 16);
}
__device__ __forceinline__ float bf2f(unsigned short h) {
    return __uint_as_float((unsigned int)h << 16);
}

// ---------- kernel 1: f32 row norms (f64 accumulate, cast f32) ----------
__global__ __launch_bounds__(256) void k_rownorm(const float* __restrict__ src,
                                                 float* __restrict__ outf) {
    int j = blockIdx.x * 4 + (threadIdx.x >> 6);
    int lane = threadIdx.x & 63;
    const float4* e4 = (const float4*)(src + (size_t)j * E_DIM);
    float4 v = e4[lane];
    double s = (double)v.x * v.x + (double)v.y * v.y + (double)v.z * v.z + (double)v.w * v.w;
    #pragma unroll
    for (int off = 1; off < 64; off <<= 1) s += __shfl_xor(s, off);
    if (lane == 0) outf[j] = (float)s;
}

// ---------- kernel 2: bf16 hi/lo split into MFMA fragment-major layout ----------
__global__ __launch_bounds__(256) void k_split(const float* __restrict__ src,
                                               unsigned short* __restrict__ hi,
                                               unsigned short* __restrict__ lo) {
    int c = blockIdx.x * 256 + threadIdx.x;   // 8-float chunk id
    int r   = c >> 5;
    int kc8 = c & 31;
    const float* p = src + (size_t)c * 8;
    float v[8];
    *(float4*)&v[0] = *(const float4*)p;
    *(float4*)&v[4] = *(const float4*)(p + 4);
    short8 h8, l8;
    #pragma unroll
    for (int t = 0; t < 8; t++) {
        unsigned short h = bfr(v[t]);
        h8[t] = (short)h;
        l8[t] = (short)bfr(v[t] - bf2f(h));
    }
    int kt = kc8 >> 2, lg = kc8 & 3;
    size_t o8 = (size_t)(r >> 4) * 512 + kt * 64 + lg * 16 + (r & 15);
    *(short8*)(hi + o8 * 8) = h8;
    *(short8*)(lo + o8 * 8) = l8;
}

// ---------- kernel 3: z-in-registers / B-through-LDS, DOUBLE-BUFFERED ----------
// Grid = 256 blocks (1/CU, all co-resident). Wave holds its 32 rows' A-frags
// in 128 VGPR (loaded once). 64-j B-tiles (64 KB hi+lo) cycle through 2 LDS
// buffers, staged with async global_load_lds (zero staging VGPRs) while the
// current tile computes. r14 lesson kept: after the z prologue the L2 carries
// only B (4 MB = per-XCD L2), so residency is capacity-guaranteed. r14 fix:
// staging was serial between barriers with 1 wave/SIMD -> 415 us of stalls.
__global__ __launch_bounds__(256, 1) void k_screen(
        const unsigned short* __restrict__ zhi, const unsigned short* __restrict__ zlo,
        const unsigned short* __restrict__ ehi, const unsigned short* __restrict__ elo,
        const float* __restrict__ enf, const float* __restrict__ znf,
        int* __restrict__ idx, int* __restrict__ flaglist, int* __restrict__ flagcnt) {
    __shared__ short8 BT[8192];                // 128 KB: 2 bufs x (2048 hi | 2048 lo)

    const int tid  = threadIdx.x;
    const int lane = tid & 63;
    const int w    = tid >> 6;                 // wave 0..3
    const int l15  = lane & 15;
    const int lg   = lane >> 4;
    const int fb0  = blockIdx.x * 8 + w * 2;   // wave's first 16-row frag block

    const short8* Ah = (const short8*)zhi;
    const short8* Al = (const short8*)zlo;
    const short8* Gh = (const short8*)ehi;
    const short8* Gl = (const short8*)elo;

    // ---- prologue: wave's 32 rows of A (hi+lo) -> 128 VGPR, loaded once ----
    short8 ah[2][8], al[2][8];
    #pragma unroll
    for (int mi = 0; mi < 2; mi++)
        #pragma unroll
        for (int kt = 0; kt < 8; kt++) {
            size_t o = (size_t)(fb0 + mi) * 512 + kt * 64 + lane;
            ah[mi][kt] = Ah[o];
            al[mi][kt] = Al[o];
        }

    float czs[8];
    #pragma unroll
    for (int mi = 0; mi < 2; mi++)
        #pragma unroll
        for (int qi = 0; qi < 4; qi++)
            czs[mi * 4 + qi] = znf[(fb0 + mi) * 16 + lg * 4 + qi];

    unsigned long long K1[8];
    float Qf[8];
    #pragma unroll
    for (int s = 0; s < 8; s++) { K1[s] = ~0ull; Qf[s] = __uint_as_float(0x7F800000u); }

    // stage tile t into buffer b: 64 chunks of 1 KB, 16 per wave (8 hi + 8 lo)
    auto stage = [&](int t, int b) {
        const short8* sh = Gh + (size_t)t * 2048;
        const short8* sl = Gl + (size_t)t * 2048;
        short8* dh = &BT[b * 4096];
        short8* dl = &BT[b * 4096 + 2048];
        #pragma unroll
        for (int i = 0; i < 8; i++) {
            int c = (w * 8 + i) * 64;          // chunk base (short8 units), wave-uniform
            GLOAD_LDS16(sh + c + lane, dh + c);
            GLOAD_LDS16(sl + c + lane, dl + c);
        }
    };

    int cur = 0;
    stage(0, 0);
    for (int t = 0; t < 64; ++t) {
        __syncthreads();                       // drains stage of buf[cur] (vmcnt0+bar)
        if (t + 1 < 64) stage(t + 1, cur ^ 1); // async: flies during compute
        const short8* Bc_h = &BT[cur * 4096];
        const short8* Bc_l = &BT[cur * 4096 + 2048];

        f32x4 acc[2][4];
        #pragma unroll
        for (int mi = 0; mi < 2; mi++)
            #pragma unroll
            for (int p = 0; p < 4; p++)
                acc[mi][p] = (f32x4){0.f, 0.f, 0.f, 0.f};

        #pragma unroll
        for (int kt = 0; kt < 8; kt++) {
            short8 bh[4], bl[4];
            #pragma unroll
            for (int p = 0; p < 4; p++) {
                bh[p] = Bc_h[p * 512 + kt * 64 + lane];
                bl[p] = Bc_l[p * 512 + kt * 64 + lane];
            }
            #pragma unroll
            for (int p = 0; p < 4; p++) {
                #pragma unroll
                for (int mi = 0; mi < 2; mi++) {
                    acc[mi][p] = __builtin_amdgcn_mfma_f32_16x16x32_bf16(ah[mi][kt], bh[p], acc[mi][p], 0, 0, 0);
                    acc[mi][p] = __builtin_amdgcn_mfma_f32_16x16x32_bf16(al[mi][kt], bh[p], acc[mi][p], 0, 0, 0);
                    acc[mi][p] = __builtin_amdgcn_mfma_f32_16x16x32_bf16(ah[mi][kt], bl[p], acc[mi][p], 0, 0, 0);
                }
            }
        }

        // ---- fold tile into running per-row (K,Q) on the collapsed grid ----
        #pragma unroll
        for (int p = 0; p < 4; p++) {
            int j = t * 64 + p * 16 + l15;
            float Ce = enf[j];
            #pragma unroll
            for (int mi = 0; mi < 2; mi++) {
                #pragma unroll
                for (int qi = 0; qi < 4; qi++) {
                    int s = mi * 4 + qi;
                    float av = acc[mi][p][qi];
                    float A  = czs[s] + Ce;                 // fl32(Cz+Ce)
                    float qv = fmaf(-2.0f, av, A);          // fl32(A-2acc)
                    unsigned long long kk =
                        ((unsigned long long)f2sort(qv) << 32) | (unsigned int)j;
                    if (kk < K1[s]) K1[s] = kk;
                    float res = (A - qv) - 2.0f * av;       // exact rounding residue
                    float u = __uint_as_float(__float_as_uint(qv) & 0x7F800000u)
                              * 1.1920929e-7f;              // ulp(qv)
                    if (fabsf(res) > fmaf(0.5f, u, -1.5e-7f))
                        Qf[s] = fminf(Qf[s], qv);
                }
            }
        }
        cur ^= 1;
    }

    // ---- final: reduce over l15 lanes; waves own disjoint rows ----
    #pragma unroll
    for (int s = 0; s < 8; s++) {
        unsigned long long K = K1[s];
        float Q = Qf[s];
        #pragma unroll
        for (int off = 1; off < 16; off <<= 1) {
            unsigned long long ok = __shfl_xor(K, off);
            float oq = __shfl_xor(Q, off);
            if (ok < K) K = ok;
            Q = fminf(Q, oq);
        }
        if (l15 == 0) {
            int row = blockIdx.x * 128 + w * 32 + (s >> 2) * 16 + lg * 4 + (s & 3);
            idx[row] = (int)(K & 0xFFFFFFFFull);
            float qwin = sort2f((unsigned int)(K >> 32));
            float u = __uint_as_float(__float_as_uint(qwin) & 0x7F800000u) * 1.1920929e-7f;
            if (Q <= fmaf(2.0f, u, qwin)) {    // fragile candidate within 2 grid steps
                int pp = atomicAdd(flagcnt, 1);
                flaglist[pp] = row;
            }
        }
    }
}

// ---------- kernel 4: exact np-replica repair ----------
// ascending-k single-acc f32 fma chain; q = fl32(fl32(Cz+Ce) - 2*acc).
__global__ __launch_bounds__(256) void k_repair(const float* __restrict__ z,
                                                const float* __restrict__ emb,
                                                const float* __restrict__ enf,
                                                const float* __restrict__ znf,
                                                const int* __restrict__ flagcnt,
                                                const int* __restrict__ flaglist,
                                                int* __restrict__ idx) {
    __shared__ float zr[4][E_DIM];
    __shared__ unsigned long long redk[4][4];   // [wave][row]
    const int tid = threadIdx.x;
    const int cnt = flagcnt[0];

    for (int base = blockIdx.x * 4; base < cnt; base += gridDim.x * 4) {
        __syncthreads();                         // protect zr/redk reuse
        int gr[4];
        #pragma unroll
        for (int r = 0; r < 4; r++) {
            int fi = base + r;
            gr[r] = flaglist[fi < cnt ? fi : base];
        }
        #pragma unroll
        for (int r = 0; r < 4; r++)
            zr[r][tid] = z[(size_t)gr[r] * E_DIM + tid];
        __syncthreads();

        float Cz[4];
        #pragma unroll
        for (int r = 0; r < 4; r++) Cz[r] = znf[gr[r]];

        unsigned long long bk[4];
        #pragma unroll
        for (int r = 0; r < 4; r++) bk[r] = ~0ull;

        #pragma unroll
        for (int g = 0; g < 4; g++) {
            const int j0 = tid + 1024 * g;       // streams j0, +256, +512, +768
            const float* e0 = emb + (size_t)(j0      ) * E_DIM;
            const float* e1 = emb + (size_t)(j0 + 256) * E_DIM;
            const float* e2 = emb + (size_t)(j0 + 512) * E_DIM;
            const float* e3 = emb + (size_t)(j0 + 768) * E_DIM;
            float a[4][4];                       // [row][stream]
            #pragma unroll
            for (int r = 0; r < 4; r++)
                #pragma unroll
                for (int s = 0; s < 4; s++) a[r][s] = 0.0f;

            #pragma unroll 4
            for (int k4 = 0; k4 < 64; k4++) {
                float4 v0 = *(const float4*)(e0 + k4 * 4);
                float4 v1 = *(const float4*)(e1 + k4 * 4);
                float4 v2 = *(const float4*)(e2 + k4 * 4);
                float4 v3 = *(const float4*)(e3 + k4 * 4);
                #pragma unroll
                for (int r = 0; r < 4; r++) {
                    float4 zq = *(const float4*)&zr[r][k4 * 4];
                    a[r][0] = fmaf(zq.x, v0.x, a[r][0]); a[r][0] = fmaf(zq.y, v0.y, a[r][0]);
                    a[r][0] = fmaf(zq.z, v0.z, a[r][0]); a[r][0] = fmaf(zq.w, v0.w, a[r][0]);
                    a[r][1] = fmaf(zq.x, v1.x, a[r][1]); a[r][1] = fmaf(zq.y, v1.y, a[r][1]);
                    a[r][1] = fmaf(zq.z, v1.z, a[r][1]); a[r][1] = fmaf(zq.w, v1.w, a[r][1]);
                    a[r][2] = fmaf(zq.x, v2.x, a[r][2]); a[r][2] = fmaf(zq.y, v2.y, a[r][2]);
                    a[r][2] = fmaf(zq.z, v2.z, a[r][2]); a[r][2] = fmaf(zq.w, v2.w, a[r][2]);
                    a[r][3] = fmaf(zq.x, v3.x, a[r][3]); a[r][3] = fmaf(zq.y, v3.y, a[r][3]);
                    a[r][3] = fmaf(zq.z, v3.z, a[r][3]); a[r][3] = fmaf(zq.w, v3.w, a[r][3]);
                }
            }
            float en[4] = {enf[j0], enf[j0 + 256], enf[j0 + 512], enf[j0 + 768]};
            #pragma unroll
            for (int r = 0; r < 4; r++) {
                #pragma unroll
                for (int s = 0; s < 4; s++) {
                    float q = (Cz[r] + en[s]) - 2.0f * a[r][s];
                    unsigned long long k =
                        ((unsigned long long)f2sort(q) << 32) | (unsigned int)(j0 + 256 * s);
                    if (k < bk[r]) bk[r] = k;
                }
            }
        }

        const int w = tid >> 6;
        #pragma unroll
        for (int r = 0; r < 4; r++) {
            unsigned long long K = bk[r];
            #pragma unroll
            for (int off = 1; off < 64; off <<= 1) {
                unsigned long long ok = __shfl_xor(K, off);
                if (ok < K) K = ok;
            }
            if ((tid & 63) == 0) redk[w][r] = K;
        }
        __syncthreads();
        if (tid < 4 && base + tid < cnt) {
            unsigned long long K = redk[0][tid];
            #pragma unroll
            for (int wv = 1; wv < 4; wv++)
                if (redk[wv][tid] < K) K = redk[wv][tid];
            idx[gr[tid]] = (int)(K & 0xFFFFFFFFull);
        }
    }
}

// ---------- kernel 5: epilogue ----------
// d_out FLOAT32: [loss(1) | one-hot(32768*4096) | z_q_st(32768*256) |
//                 emb(4096*256) | indices(32768)]
__global__ __launch_bounds__(256) void k_epilogue(const float* __restrict__ z,
                                                  const float* __restrict__ emb,
                                                  const int* __restrict__ idx,
                                                  float* __restrict__ out,
                                                  double* __restrict__ rowloss) {
    const int row  = blockIdx.x * 4 + (threadIdx.x >> 6);
    const int lane = threadIdx.x & 63;
    const int j    = idx[row];
    float4 zv = *(const float4*)(z   + (size_t)row * E_DIM + lane * 4);
    float4 ev = *(const float4*)(emb + (size_t)j   * E_DIM + lane * 4);

    float4 st;
    st.x = zv.x + (ev.x - zv.x);
    st.y = zv.y + (ev.y - zv.y);
    st.z = zv.z + (ev.z - zv.z);
    st.w = zv.w + (ev.w - zv.w);
    const size_t zq0 = 1ull + (size_t)N_ROWS * N_E;
    *(float4*)(out + zq0 + (size_t)row * E_DIM + lane * 4) = st;

    double dx = (double)ev.x - zv.x, dy = (double)ev.y - zv.y;
    double dz = (double)ev.z - zv.z, dw = (double)ev.w - zv.w;
    double s = dx * dx + dy * dy + dz * dz + dw * dw;
    #pragma unroll
    for (int off = 1; off < 64; off <<= 1) s += __shfl_xor(s, off);

    if (lane == 0) {
        rowloss[row] = s;
        out[1ull + (size_t)row * N_E + j] = 1.0f;
        const size_t ix0 = 1ull + (size_t)N_ROWS * N_E + (size_t)N_ROWS * E_DIM
                         + (size_t)N_E * E_DIM;
        out[ix0 + row] = (float)j;
    }
}

// ---------- kernel 6: deterministic loss reduce ----------
__global__ __launch_bounds__(256) void k_loss(const double* __restrict__ rowloss,
                                              float* __restrict__ out) {
    __shared__ double sm[256];
    double s = 0.0;
    for (int i = threadIdx.x; i < N_ROWS; i += 256) s += rowloss[i];
    sm[threadIdx.x] = s;
    __syncthreads();
    for (int h = 128; h > 0; h >>= 1) {
        if (threadIdx.x < h) sm[threadIdx.x] += sm[threadIdx.x + h];
        __syncthreads();
    }
    if (threadIdx.x == 0)
        out[0] = (float)(sm[0] / ((double)N_ROWS * (double)E_DIM));
}

extern "C" void kernel_launch(void* const* d_in, const int* in_sizes, int n_in,
                              void* d_out, int out_size, void* d_ws, size_t ws_size,
                              hipStream_t stream) {
    const float* z   = (const float*)d_in[0];
    const float* emb = (const float*)d_in[1];
    float* out = (float*)d_out;

    // workspace layout (disjoint, 16B-aligned)
    char* ws = (char*)d_ws;
    float*          enf      = (float*)(ws + 0);                  // 16 KB   -> 16384
    float*          znf      = (float*)(ws + 16384);              // 128 KB  -> 147456
    int*            idx      = (int*)(ws + 147456);               // 128 KB  -> 278528
    int*            flagcnt  = (int*)(ws + 278528);               // 128 B   -> 278656
    int*            flaglist = (int*)(ws + 278656);               // 128 KB  -> 409728
    double*         rowloss  = (double*)(ws + 409728);            // 256 KB  -> 671872
    unsigned short* zhi      = (unsigned short*)(ws + 671872);    // 16 MB   -> 17449088
    unsigned short* zlo      = (unsigned short*)(ws + 17449088);  // 16 MB   -> 34226304
    unsigned short* ehi      = (unsigned short*)(ws + 34226304);  // 2 MB    -> 36323456
    unsigned short* elo      = (unsigned short*)(ws + 36323456);  // 2 MB    -> 38420608

    // zero one-hot region + flag counter
    hipMemsetAsync(out + 1, 0, (size_t)N_ROWS * (size_t)N_E * sizeof(float), stream);
    hipMemsetAsync(flagcnt, 0, sizeof(int), stream);

    // emb passthrough chunk: exact d2d copy
    const size_t emb0 = 1ull + (size_t)N_ROWS * N_E + (size_t)N_ROWS * E_DIM;
    hipMemcpyAsync(out + emb0, emb, (size_t)N_E * E_DIM * sizeof(float),
                   hipMemcpyDeviceToDevice, stream);

    k_rownorm <<<N_E / 4, 256, 0, stream>>>(emb, enf);
    k_rownorm <<<N_ROWS / 4, 256, 0, stream>>>(z, znf);
    k_split   <<<N_E / 8, 256, 0, stream>>>(emb, ehi, elo);
    k_split   <<<N_ROWS / 8, 256, 0, stream>>>(z, zhi, zlo);
    // z-in-registers / B-through-LDS double-buffered screener: grid == CU count
    k_screen  <<<256, 256, 0, stream>>>(zhi, zlo, ehi, elo, enf, znf,
                                        idx, flaglist, flagcnt);
    k_repair  <<<1024, 256, 0, stream>>>(z, emb, enf, znf, flagcnt, flaglist, idx);
    k_epilogue<<<N_ROWS / 4, 256, 0, stream>>>(z, emb, idx, out, rowloss);
    k_loss    <<<1, 256, 0, stream>>>(rowloss, out);
}

// Round 16
// 583.972 us; speedup vs baseline: 3.1639x; 1.0216x over previous
//
#include <hip/hip_runtime.h>
#include <stdint.h>

#define N_ROWS 32768
#define N_E    4096
#define E_DIM  256

typedef __attribute__((ext_vector_type(8))) short short8;
typedef __attribute__((ext_vector_type(4))) float f32x4;

// async global->LDS 16B: dest = wave-uniform LDS base + lane*16
#define GLOAD_LDS16(g, l)                                                     \
    __builtin_amdgcn_global_load_lds(                                         \
        (const __attribute__((address_space(1))) void*)(g),                   \
        (__attribute__((address_space(3))) void*)(l), 16, 0, 0)

// sortable-uint encoding: order-preserving float -> uint
__device__ __forceinline__ unsigned int f2sort(float s) {
    unsigned int b = __float_as_uint(s);
    return (b & 0x80000000u) ? ~b : (b | 0x80000000u);
}
__device__ __forceinline__ float sort2f(unsigned int u) {
    unsigned int b = (u & 0x80000000u) ? (u ^ 0x80000000u) : ~u;
    return __uint_as_float(b);
}
__device__ __forceinline__ unsigned short bfr(float x) {   // f32 -> bf16 RNE
    unsigned int u = __float_as_uint(x);
    return (unsigned short)((u + 0x7fffu + ((u >> 16) & 1u)) >> 16);
}
__device__ __forceinline__ float bf2f(unsigned short h) {
    return __uint_as_float((unsigned int)h << 16);
}

// ---------- kernel 1: f32 row norms (f64 accumulate, cast f32) ----------
__global__ __launch_bounds__(256) void k_rownorm(const float* __restrict__ src,
                                                 float* __restrict__ outf) {
    int j = blockIdx.x * 4 + (threadIdx.x >> 6);
    int lane = threadIdx.x & 63;
    const float4* e4 = (const float4*)(src + (size_t)j * E_DIM);
    float4 v = e4[lane];
    double s = (double)v.x * v.x + (double)v.y * v.y + (double)v.z * v.z + (double)v.w * v.w;
    #pragma unroll
    for (int off = 1; off < 64; off <<= 1) s += __shfl_xor(s, off);
    if (lane == 0) outf[j] = (float)s;
}

// ---------- kernel 2: bf16 hi/lo split into MFMA fragment-major layout (emb) ----------
__global__ __launch_bounds__(256) void k_split(const float* __restrict__ src,
                                               unsigned short* __restrict__ hi,
                                               unsigned short* __restrict__ lo) {
    int c = blockIdx.x * 256 + threadIdx.x;   // 8-float chunk id
    int r   = c >> 5;
    int kc8 = c & 31;
    const float* p = src + (size_t)c * 8;
    float v[8];
    *(float4*)&v[0] = *(const float4*)p;
    *(float4*)&v[4] = *(const float4*)(p + 4);
    short8 h8, l8;
    #pragma unroll
    for (int t = 0; t < 8; t++) {
        unsigned short h = bfr(v[t]);
        h8[t] = (short)h;
        l8[t] = (short)bfr(v[t] - bf2f(h));
    }
    int kt = kc8 >> 2, lg = kc8 & 3;
    size_t o8 = (size_t)(r >> 4) * 512 + kt * 64 + lg * 16 + (r & 15);
    *(short8*)(hi + o8 * 8) = h8;
    *(short8*)(lo + o8 * 8) = l8;
}

// ---------- kernel 3: z-in-registers / B-through-LDS, dbuf + kt-pipelined ----------
// Grid = 256 (1 block/CU, co-resident). Wave's 32 rows of A split in-prologue
// from raw z into 128 VGPR. 64-j B-tiles via async global_load_lds, double-
// buffered. r15 lesson: 1 wave/SIMD is forced (LDS-duplication floor), so
// ds_read latency must be hidden by ILP -> explicit 2-deep b-register
// pipeline (named sets, compile-time indexed).
__global__ __launch_bounds__(256, 1) void k_screen(
        const float* __restrict__ z,
        const unsigned short* __restrict__ ehi, const unsigned short* __restrict__ elo,
        const float* __restrict__ enf, const float* __restrict__ znf,
        int* __restrict__ idx, int* __restrict__ flaglist, int* __restrict__ flagcnt) {
    __shared__ short8 BT[8192];                // 128 KB: 2 bufs x (2048 hi | 2048 lo)

    const int tid  = threadIdx.x;
    const int lane = tid & 63;
    const int w    = tid >> 6;                 // wave 0..3
    const int l15  = lane & 15;
    const int lg   = lane >> 4;
    const int fb0  = blockIdx.x * 8 + w * 2;   // wave's first 16-row frag block

    const short8* Gh = (const short8*)ehi;
    const short8* Gl = (const short8*)elo;

    // ---- prologue: read z rows, split hi/lo in-register -> A-frags (once) ----
    short8 ah[2][8], al[2][8];
    #pragma unroll
    for (int mi = 0; mi < 2; mi++) {
        int row = (fb0 + mi) * 16 + l15;
        const float* zr = z + (size_t)row * E_DIM + lg * 8;
        #pragma unroll
        for (int kt = 0; kt < 8; kt++) {
            float4 v0 = *(const float4*)(zr + kt * 32);
            float4 v1 = *(const float4*)(zr + kt * 32 + 4);
            float v[8] = {v0.x, v0.y, v0.z, v0.w, v1.x, v1.y, v1.z, v1.w};
            short8 h8, l8;
            #pragma unroll
            for (int t = 0; t < 8; t++) {
                unsigned short h = bfr(v[t]);
                h8[t] = (short)h;
                l8[t] = (short)bfr(v[t] - bf2f(h));
            }
            ah[mi][kt] = h8;
            al[mi][kt] = l8;
        }
    }

    float czs[8];
    #pragma unroll
    for (int mi = 0; mi < 2; mi++)
        #pragma unroll
        for (int qi = 0; qi < 4; qi++)
            czs[mi * 4 + qi] = znf[(fb0 + mi) * 16 + lg * 4 + qi];

    unsigned long long K1[8];
    float Qf[8];
    #pragma unroll
    for (int s = 0; s < 8; s++) { K1[s] = ~0ull; Qf[s] = __uint_as_float(0x7F800000u); }

    // stage tile t into buffer b: 64 chunks of 1 KB, 16 per wave (8 hi + 8 lo)
    auto stage = [&](int t, int b) {
        const short8* sh = Gh + (size_t)t * 2048;
        const short8* sl = Gl + (size_t)t * 2048;
        short8* dh = &BT[b * 4096];
        short8* dl = &BT[b * 4096 + 2048];
        #pragma unroll
        for (int i = 0; i < 8; i++) {
            int c = (w * 8 + i) * 64;          // chunk base (short8 units), wave-uniform
            GLOAD_LDS16(sh + c + lane, dh + c);
            GLOAD_LDS16(sl + c + lane, dl + c);
        }
    };

#define LOADB(BH, BL, KT)                                                     \
    _Pragma("unroll")                                                         \
    for (int p = 0; p < 4; p++) {                                             \
        BH[p] = Bc_h[p * 512 + (KT) * 64 + lane];                             \
        BL[p] = Bc_l[p * 512 + (KT) * 64 + lane];                             \
    }
#define DOMFMA(BH, BL, KT)                                                    \
    _Pragma("unroll")                                                         \
    for (int p = 0; p < 4; p++) {                                             \
        _Pragma("unroll")                                                     \
        for (int mi = 0; mi < 2; mi++) {                                      \
            acc[mi][p] = __builtin_amdgcn_mfma_f32_16x16x32_bf16(ah[mi][KT], BH[p], acc[mi][p], 0, 0, 0); \
            acc[mi][p] = __builtin_amdgcn_mfma_f32_16x16x32_bf16(al[mi][KT], BH[p], acc[mi][p], 0, 0, 0); \
            acc[mi][p] = __builtin_amdgcn_mfma_f32_16x16x32_bf16(ah[mi][KT], BL[p], acc[mi][p], 0, 0, 0); \
        }                                                                     \
    }

    int cur = 0;
    stage(0, 0);
    for (int t = 0; t < 64; ++t) {
        __syncthreads();                       // drains stage of buf[cur]
        if (t + 1 < 64) stage(t + 1, cur ^ 1); // async: flies during compute
        const short8* Bc_h = &BT[cur * 4096];
        const short8* Bc_l = &BT[cur * 4096 + 2048];

        f32x4 acc[2][4];
        #pragma unroll
        for (int mi = 0; mi < 2; mi++)
            #pragma unroll
            for (int p = 0; p < 4; p++)
                acc[mi][p] = (f32x4){0.f, 0.f, 0.f, 0.f};

        // 2-deep kt pipeline: loads for kt+1/kt+2 fly under kt's 24 MFMAs
        short8 bhA[4], blA[4], bhB[4], blB[4];
        LOADB(bhA, blA, 0)
        LOADB(bhB, blB, 1)
        DOMFMA(bhA, blA, 0) LOADB(bhA, blA, 2)
        DOMFMA(bhB, blB, 1) LOADB(bhB, blB, 3)
        DOMFMA(bhA, blA, 2) LOADB(bhA, blA, 4)
        DOMFMA(bhB, blB, 3) LOADB(bhB, blB, 5)
        DOMFMA(bhA, blA, 4) LOADB(bhA, blA, 6)
        DOMFMA(bhB, blB, 5) LOADB(bhB, blB, 7)
        DOMFMA(bhA, blA, 6)
        DOMFMA(bhB, blB, 7)

        // ---- fold tile into running per-row (K,Q) on the collapsed grid ----
        #pragma unroll
        for (int p = 0; p < 4; p++) {
            int j = t * 64 + p * 16 + l15;
            float Ce = enf[j];
            #pragma unroll
            for (int mi = 0; mi < 2; mi++) {
                #pragma unroll
                for (int qi = 0; qi < 4; qi++) {
                    int s = mi * 4 + qi;
                    float av = acc[mi][p][qi];
                    float A  = czs[s] + Ce;                 // fl32(Cz+Ce)
                    float qv = fmaf(-2.0f, av, A);          // fl32(A-2acc)
                    unsigned long long kk =
                        ((unsigned long long)f2sort(qv) << 32) | (unsigned int)j;
                    if (kk < K1[s]) K1[s] = kk;
                    float res = (A - qv) - 2.0f * av;       // exact rounding residue
                    float u = __uint_as_float(__float_as_uint(qv) & 0x7F800000u)
                              * 1.1920929e-7f;              // ulp(qv)
                    if (fabsf(res) > fmaf(0.5f, u, -1.5e-7f))
                        Qf[s] = fminf(Qf[s], qv);
                }
            }
        }
        cur ^= 1;
    }
#undef LOADB
#undef DOMFMA

    // ---- final: reduce over l15 lanes; waves own disjoint rows ----
    #pragma unroll
    for (int s = 0; s < 8; s++) {
        unsigned long long K = K1[s];
        float Q = Qf[s];
        #pragma unroll
        for (int off = 1; off < 16; off <<= 1) {
            unsigned long long ok = __shfl_xor(K, off);
            float oq = __shfl_xor(Q, off);
            if (ok < K) K = ok;
            Q = fminf(Q, oq);
        }
        if (l15 == 0) {
            int row = blockIdx.x * 128 + w * 32 + (s >> 2) * 16 + lg * 4 + (s & 3);
            idx[row] = (int)(K & 0xFFFFFFFFull);
            float qwin = sort2f((unsigned int)(K >> 32));
            float u = __uint_as_float(__float_as_uint(qwin) & 0x7F800000u) * 1.1920929e-7f;
            if (Q <= fmaf(2.0f, u, qwin)) {    // fragile candidate within 2 grid steps
                int pp = atomicAdd(flagcnt, 1);
                flaglist[pp] = row;
            }
        }
    }
}

// ---------- kernel 4: exact np-replica repair ----------
// ascending-k single-acc f32 fma chain; q = fl32(fl32(Cz+Ce) - 2*acc).
__global__ __launch_bounds__(256) void k_repair(const float* __restrict__ z,
                                                const float* __restrict__ emb,
                                                const float* __restrict__ enf,
                                                const float* __restrict__ znf,
                                                const int* __restrict__ flagcnt,
                                                const int* __restrict__ flaglist,
                                                int* __restrict__ idx) {
    __shared__ float zr[4][E_DIM];
    __shared__ unsigned long long redk[4][4];   // [wave][row]
    const int tid = threadIdx.x;
    const int cnt = flagcnt[0];

    for (int base = blockIdx.x * 4; base < cnt; base += gridDim.x * 4) {
        __syncthreads();                         // protect zr/redk reuse
        int gr[4];
        #pragma unroll
        for (int r = 0; r < 4; r++) {
            int fi = base + r;
            gr[r] = flaglist[fi < cnt ? fi : base];
        }
        #pragma unroll
        for (int r = 0; r < 4; r++)
            zr[r][tid] = z[(size_t)gr[r] * E_DIM + tid];
        __syncthreads();

        float Cz[4];
        #pragma unroll
        for (int r = 0; r < 4; r++) Cz[r] = znf[gr[r]];

        unsigned long long bk[4];
        #pragma unroll
        for (int r = 0; r < 4; r++) bk[r] = ~0ull;

        #pragma unroll
        for (int g = 0; g < 4; g++) {
            const int j0 = tid + 1024 * g;       // streams j0, +256, +512, +768
            const float* e0 = emb + (size_t)(j0      ) * E_DIM;
            const float* e1 = emb + (size_t)(j0 + 256) * E_DIM;
            const float* e2 = emb + (size_t)(j0 + 512) * E_DIM;
            const float* e3 = emb + (size_t)(j0 + 768) * E_DIM;
            float a[4][4];                       // [row][stream]
            #pragma unroll
            for (int r = 0; r < 4; r++)
                #pragma unroll
                for (int s = 0; s < 4; s++) a[r][s] = 0.0f;

            #pragma unroll 4
            for (int k4 = 0; k4 < 64; k4++) {
                float4 v0 = *(const float4*)(e0 + k4 * 4);
                float4 v1 = *(const float4*)(e1 + k4 * 4);
                float4 v2 = *(const float4*)(e2 + k4 * 4);
                float4 v3 = *(const float4*)(e3 + k4 * 4);
                #pragma unroll
                for (int r = 0; r < 4; r++) {
                    float4 zq = *(const float4*)&zr[r][k4 * 4];
                    a[r][0] = fmaf(zq.x, v0.x, a[r][0]); a[r][0] = fmaf(zq.y, v0.y, a[r][0]);
                    a[r][0] = fmaf(zq.z, v0.z, a[r][0]); a[r][0] = fmaf(zq.w, v0.w, a[r][0]);
                    a[r][1] = fmaf(zq.x, v1.x, a[r][1]); a[r][1] = fmaf(zq.y, v1.y, a[r][1]);
                    a[r][1] = fmaf(zq.z, v1.z, a[r][1]); a[r][1] = fmaf(zq.w, v1.w, a[r][1]);
                    a[r][2] = fmaf(zq.x, v2.x, a[r][2]); a[r][2] = fmaf(zq.y, v2.y, a[r][2]);
                    a[r][2] = fmaf(zq.z, v2.z, a[r][2]); a[r][2] = fmaf(zq.w, v2.w, a[r][2]);
                    a[r][3] = fmaf(zq.x, v3.x, a[r][3]); a[r][3] = fmaf(zq.y, v3.y, a[r][3]);
                    a[r][3] = fmaf(zq.z, v3.z, a[r][3]); a[r][3] = fmaf(zq.w, v3.w, a[r][3]);
                }
            }
            float en[4] = {enf[j0], enf[j0 + 256], enf[j0 + 512], enf[j0 + 768]};
            #pragma unroll
            for (int r = 0; r < 4; r++) {
                #pragma unroll
                for (int s = 0; s < 4; s++) {
                    float q = (Cz[r] + en[s]) - 2.0f * a[r][s];
                    unsigned long long k =
                        ((unsigned long long)f2sort(q) << 32) | (unsigned int)(j0 + 256 * s);
                    if (k < bk[r]) bk[r] = k;
                }
            }
        }

        const int w = tid >> 6;
        #pragma unroll
        for (int r = 0; r < 4; r++) {
            unsigned long long K = bk[r];
            #pragma unroll
            for (int off = 1; off < 64; off <<= 1) {
                unsigned long long ok = __shfl_xor(K, off);
                if (ok < K) K = ok;
            }
            if ((tid & 63) == 0) redk[w][r] = K;
        }
        __syncthreads();
        if (tid < 4 && base + tid < cnt) {
            unsigned long long K = redk[0][tid];
            #pragma unroll
            for (int wv = 1; wv < 4; wv++)
                if (redk[wv][tid] < K) K = redk[wv][tid];
            idx[gr[tid]] = (int)(K & 0xFFFFFFFFull);
        }
    }
}

// ---------- kernel 5: epilogue ----------
// d_out FLOAT32: [loss(1) | one-hot(32768*4096) | z_q_st(32768*256) |
//                 emb(4096*256) | indices(32768)]
__global__ __launch_bounds__(256) void k_epilogue(const float* __restrict__ z,
                                                  const float* __restrict__ emb,
                                                  const int* __restrict__ idx,
                                                  float* __restrict__ out,
                                                  double* __restrict__ rowloss) {
    const int row  = blockIdx.x * 4 + (threadIdx.x >> 6);
    const int lane = threadIdx.x & 63;
    const int j    = idx[row];
    float4 zv = *(const float4*)(z   + (size_t)row * E_DIM + lane * 4);
    float4 ev = *(const float4*)(emb + (size_t)j   * E_DIM + lane * 4);

    float4 st;
    st.x = zv.x + (ev.x - zv.x);
    st.y = zv.y + (ev.y - zv.y);
    st.z = zv.z + (ev.z - zv.z);
    st.w = zv.w + (ev.w - zv.w);
    const size_t zq0 = 1ull + (size_t)N_ROWS * N_E;
    *(float4*)(out + zq0 + (size_t)row * E_DIM + lane * 4) = st;

    double dx = (double)ev.x - zv.x, dy = (double)ev.y - zv.y;
    double dz = (double)ev.z - zv.z, dw = (double)ev.w - zv.w;
    double s = dx * dx + dy * dy + dz * dz + dw * dw;
    #pragma unroll
    for (int off = 1; off < 64; off <<= 1) s += __shfl_xor(s, off);

    if (lane == 0) {
        rowloss[row] = s;
        out[1ull + (size_t)row * N_E + j] = 1.0f;
        const size_t ix0 = 1ull + (size_t)N_ROWS * N_E + (size_t)N_ROWS * E_DIM
                         + (size_t)N_E * E_DIM;
        out[ix0 + row] = (float)j;
    }
}

// ---------- kernel 6: deterministic loss reduce ----------
__global__ __launch_bounds__(256) void k_loss(const double* __restrict__ rowloss,
                                              float* __restrict__ out) {
    __shared__ double sm[256];
    double s = 0.0;
    for (int i = threadIdx.x; i < N_ROWS; i += 256) s += rowloss[i];
    sm[threadIdx.x] = s;
    __syncthreads();
    for (int h = 128; h > 0; h >>= 1) {
        if (threadIdx.x < h) sm[threadIdx.x] += sm[threadIdx.x + h];
        __syncthreads();
    }
    if (threadIdx.x == 0)
        out[0] = (float)(sm[0] / ((double)N_ROWS * (double)E_DIM));
}

extern "C" void kernel_launch(void* const* d_in, const int* in_sizes, int n_in,
                              void* d_out, int out_size, void* d_ws, size_t ws_size,
                              hipStream_t stream) {
    const float* z   = (const float*)d_in[0];
    const float* emb = (const float*)d_in[1];
    float* out = (float*)d_out;

    // workspace layout (disjoint, 16B-aligned)
    char* ws = (char*)d_ws;
    float*          enf      = (float*)(ws + 0);                  // 16 KB   -> 16384
    float*          znf      = (float*)(ws + 16384);              // 128 KB  -> 147456
    int*            idx      = (int*)(ws + 147456);               // 128 KB  -> 278528
    int*            flagcnt  = (int*)(ws + 278528);               // 128 B   -> 278656
    int*            flaglist = (int*)(ws + 278656);               // 128 KB  -> 409728
    double*         rowloss  = (double*)(ws + 409728);            // 256 KB  -> 671872
    unsigned short* ehi      = (unsigned short*)(ws + 671872);    // 2 MB    -> 2769024
    unsigned short* elo      = (unsigned short*)(ws + 2769024);   // 2 MB    -> 4866176

    // zero one-hot region + flag counter
    hipMemsetAsync(out + 1, 0, (size_t)N_ROWS * (size_t)N_E * sizeof(float), stream);
    hipMemsetAsync(flagcnt, 0, sizeof(int), stream);

    // emb passthrough chunk: exact d2d copy
    const size_t emb0 = 1ull + (size_t)N_ROWS * N_E + (size_t)N_ROWS * E_DIM;
    hipMemcpyAsync(out + emb0, emb, (size_t)N_E * E_DIM * sizeof(float),
                   hipMemcpyDeviceToDevice, stream);

    k_rownorm <<<N_E / 4, 256, 0, stream>>>(emb, enf);
    k_rownorm <<<N_ROWS / 4, 256, 0, stream>>>(z, znf);
    k_split   <<<N_E / 8, 256, 0, stream>>>(emb, ehi, elo);
    // z-in-registers / B-through-LDS dbuf screener, kt-pipelined; grid == CU count
    k_screen  <<<256, 256, 0, stream>>>(z, ehi, elo, enf, znf,
                                        idx, flaglist, flagcnt);
    k_repair  <<<1024, 256, 0, stream>>>(z, emb, enf, znf, flagcnt, flaglist, idx);
    k_epilogue<<<N_ROWS / 4, 256, 0, stream>>>(z, emb, idx, out, rowloss);
    k_loss    <<<1, 256, 0, stream>>>(rowloss, out);
}